// Round 2
// baseline (1279.356 us; speedup 1.0000x reference)
//
#include <hip/hip_runtime.h>
#include <hip/hip_bf16.h>
#include <math.h>

#define NB    64      // graphs
#define NPG   512     // nodes per graph
#define NN    (NB*NPG)   // 32768 nodes
#define NE    524288  // edges per branch
#define HD    128     // hidden dim
#define KP    30      // sort-pool k
#define CT    26      // K-4 conv output length
#define CO    32      // conv out channels
#define FEAT  (CO*CT) // 832 branch feature size

typedef short v8s __attribute__((ext_vector_type(8)));
typedef float v4f __attribute__((ext_vector_type(4)));

__device__ __forceinline__ unsigned short f2bf_rne(float x) {
    union { float f; unsigned u; } a; a.f = x;
    return (unsigned short)((a.u + 0x7fffu + ((a.u >> 16) & 1u)) >> 16);
}
__device__ __forceinline__ float bf2f(unsigned short b) {
    union { float f; unsigned u; } a; a.u = ((unsigned)b) << 16; return a.f;
}

// ---------------------------------------------------------------------------
// CSR build
// ---------------------------------------------------------------------------
__global__ void count_k(const int* __restrict__ edges, int* __restrict__ counts) {
    int e = blockIdx.x * 256 + threadIdx.x;
    atomicAdd(&counts[edges[NE + e]], 1);
}

__global__ __launch_bounds__(1024) void scan_k(const int* __restrict__ counts,
                                               int* __restrict__ offs,
                                               int* __restrict__ cursor) {
    __shared__ int sd[1024];
    __shared__ int carry_s;
    int t = threadIdx.x;
    if (t == 0) carry_s = 0;
    __syncthreads();
    for (int ch = 0; ch < NN / 1024; ++ch) {
        int v = counts[ch * 1024 + t];
        sd[t] = v;
        __syncthreads();
        for (int off = 1; off < 1024; off <<= 1) {
            int x = (t >= off) ? sd[t - off] : 0;
            __syncthreads();
            sd[t] += x;
            __syncthreads();
        }
        int carry = carry_s;
        int excl = carry + sd[t] - v;
        offs[ch * 1024 + t] = excl;
        cursor[ch * 1024 + t] = excl;
        __syncthreads();
        if (t == 1023) carry_s = carry + sd[1023];
        __syncthreads();
    }
    if (t == 1023) offs[NN] = carry_s;
}

__global__ void fill_k(const int* __restrict__ edges, int* __restrict__ cursor,
                       int* __restrict__ csr_src) {
    int e = blockIdx.x * 256 + threadIdx.x;
    int d = edges[NE + e];
    int p = atomicAdd(&cursor[d], 1);
    csr_src[p] = edges[e];
}

__global__ void dis_k(const int* __restrict__ counts, float* __restrict__ dis) {
    int n = blockIdx.x * 256 + threadIdx.x;
    dis[n] = rsqrtf((float)counts[n] + 1.0f);
}

// ---------------------------------------------------------------------------
// Weight prep: split fp32 W[l][k][n] into bf16 hi/lo, stored TRANSPOSED:
// hiT[l][n][k], loT[l][n][k]  (so MFMA B-fragments read contiguous k)
// ---------------------------------------------------------------------------
__global__ __launch_bounds__(256) void wprep_k(const float* __restrict__ W,
                                               unsigned short* __restrict__ hiT,
                                               unsigned short* __restrict__ loT) {
    int idx = blockIdx.x * 256 + threadIdx.x;       // 0..65535
    int l = idx >> 14, r = idx & 16383;
    int k = r >> 7, n = r & 127;
    float x = W[idx];
    unsigned short h = f2bf_rne(x);
    float rem = x - bf2f(h);
    unsigned short lo = f2bf_rne(rem);
    size_t o = ((size_t)l << 14) + n * HD + k;
    hiT[o] = h;
    loT[o] = lo;
}

// ---------------------------------------------------------------------------
// MFMA GEMM: C[M][128] = X[M][128] @ W[128][128], fp32 via split-bf16.
// grid = M/128 (=256), block = 256 (4 waves). Each wave owns a 64x64 quadrant.
// X converted fp32->hi/lo bf16 into XOR-swizzled LDS; W pre-split (wprep_k).
// ---------------------------------------------------------------------------
__global__ __launch_bounds__(256) void gemm_mfma(const float* __restrict__ X,
                                                 const unsigned short* __restrict__ WhiT,
                                                 const unsigned short* __restrict__ WloT,
                                                 float* __restrict__ C) {
    __shared__ __align__(16) unsigned short Xhi[128 * HD];
    __shared__ __align__(16) unsigned short Xlo[128 * HD];
    __shared__ __align__(16) unsigned short Bhi[128 * HD];
    __shared__ __align__(16) unsigned short Blo[128 * HD];

    int t = threadIdx.x;
    size_t r0 = (size_t)blockIdx.x * 128;

    // stage X (fp32 -> hi/lo bf16), swizzled: short_idx ^= (row&7)<<3
    const float4* Xg = (const float4*)(X + r0 * HD);
    #pragma unroll
    for (int i = 0; i < 16; ++i) {
        int f = t + i * 256;            // 0..4095 float4 slots
        int row = f >> 5, c4 = f & 31;
        float4 v = Xg[f];
        unsigned short h0 = f2bf_rne(v.x), h1 = f2bf_rne(v.y),
                       h2 = f2bf_rne(v.z), h3 = f2bf_rne(v.w);
        unsigned short l0 = f2bf_rne(v.x - bf2f(h0)), l1 = f2bf_rne(v.y - bf2f(h1)),
                       l2 = f2bf_rne(v.z - bf2f(h2)), l3 = f2bf_rne(v.w - bf2f(h3));
        int sidx = (row * HD + c4 * 4) ^ ((row & 7) << 3);
        *(ushort4*)&Xhi[sidx] = make_ushort4(h0, h1, h2, h3);
        *(ushort4*)&Xlo[sidx] = make_ushort4(l0, l1, l2, l3);
    }
    // stage W^T (already bf16 hi/lo in global), swizzled
    const uint4* WhiG = (const uint4*)WhiT;
    const uint4* WloG = (const uint4*)WloT;
    #pragma unroll
    for (int i = 0; i < 8; ++i) {
        int f = t + i * 256;            // 0..2047 16B chunks
        int n = f >> 4, k8 = f & 15;
        int sidx = (n * HD + k8 * 8) ^ ((n & 7) << 3);
        *(uint4*)&Bhi[sidx] = WhiG[f];
        *(uint4*)&Blo[sidx] = WloG[f];
    }
    __syncthreads();

    int lane = t & 63, wv = t >> 6;
    int wr = (wv >> 1) * 64, wc = (wv & 1) * 64;
    int fr = lane & 15, fq = lane >> 4;   // fragment row / k-quarter

    v4f acc[4][4];
    #pragma unroll
    for (int m = 0; m < 4; ++m)
        #pragma unroll
        for (int n = 0; n < 4; ++n)
            acc[m][n] = (v4f){0.f, 0.f, 0.f, 0.f};

    #pragma unroll
    for (int kk = 0; kk < 4; ++kk) {
        int k0 = kk * 32 + fq * 8;
        v8s ahi[4], alo[4], bhi[4], blo[4];
        #pragma unroll
        for (int m = 0; m < 4; ++m) {
            int row = wr + m * 16 + fr;
            int sidx = (row * HD + k0) ^ ((row & 7) << 3);
            ahi[m] = *(const v8s*)&Xhi[sidx];
            alo[m] = *(const v8s*)&Xlo[sidx];
        }
        #pragma unroll
        for (int n = 0; n < 4; ++n) {
            int rowb = wc + n * 16 + fr;
            int sidx = (rowb * HD + k0) ^ ((rowb & 7) << 3);
            bhi[n] = *(const v8s*)&Bhi[sidx];
            blo[n] = *(const v8s*)&Blo[sidx];
        }
        #pragma unroll
        for (int m = 0; m < 4; ++m)
            #pragma unroll
            for (int n = 0; n < 4; ++n) {
                acc[m][n] = __builtin_amdgcn_mfma_f32_16x16x32_bf16(ahi[m], bhi[n], acc[m][n], 0, 0, 0);
                acc[m][n] = __builtin_amdgcn_mfma_f32_16x16x32_bf16(ahi[m], blo[n], acc[m][n], 0, 0, 0);
                acc[m][n] = __builtin_amdgcn_mfma_f32_16x16x32_bf16(alo[m], bhi[n], acc[m][n], 0, 0, 0);
            }
    }

    // C/D layout: col = lane&15, row = (lane>>4)*4 + reg
    #pragma unroll
    for (int m = 0; m < 4; ++m)
        #pragma unroll
        for (int n = 0; n < 4; ++n)
            #pragma unroll
            for (int rg = 0; rg < 4; ++rg)
                C[(r0 + wr + m * 16 + fq * 4 + rg) * HD + wc + n * 16 + fr] = acc[m][n][rg];
}

// ---------------------------------------------------------------------------
// GCN aggregation + self-loop + bias + relu. 2 nodes per 256-thread block.
// ---------------------------------------------------------------------------
__global__ __launch_bounds__(256) void agg_relu(const float* __restrict__ xw,
                                                const int* __restrict__ csr_src,
                                                const int* __restrict__ offs,
                                                const float* __restrict__ dis,
                                                const float* __restrict__ bias,
                                                float* __restrict__ out) {
    int node = blockIdx.x * 2 + (threadIdx.x >> 7);
    int ch = threadIdx.x & 127;
    float dn = dis[node];
    int e0 = offs[node], e1 = offs[node + 1];
    float acc = 0.f;
    for (int e = e0; e < e1; ++e) {
        int s = csr_src[e];
        acc += dis[s] * xw[(size_t)s * HD + ch];
    }
    float v = acc * dn + xw[(size_t)node * HD + ch] * (dn * dn) + bias[ch];
    out[(size_t)node * HD + ch] = v > 0.f ? v : 0.f;
}

// ---------------------------------------------------------------------------
// sort_pool: per graph, bitonic sort 512 (value=ch127, idx) pairs,
// descending by value, ties -> lower index (matches jax.lax.top_k).
// ---------------------------------------------------------------------------
__global__ __launch_bounds__(512) void sort_pool_k(const float* __restrict__ x,
                                                   int* __restrict__ tk) {
    __shared__ float v[512];
    __shared__ int idx[512];
    int g = blockIdx.x, t = threadIdx.x;
    v[t] = x[(size_t)(g * NPG + t) * HD + (HD - 1)];
    idx[t] = t;
    __syncthreads();
    for (int k = 2; k <= 512; k <<= 1) {
        for (int j = k >> 1; j > 0; j >>= 1) {
            int ixj = t ^ j;
            if (ixj > t) {
                float va = v[t], vb = v[ixj];
                int ia = idx[t], ib = idx[ixj];
                bool aBefore = (va > vb) || (va == vb && ia < ib);
                bool dirDesc = ((t & k) == 0);
                if (dirDesc ? !aBefore : aBefore) {
                    v[t] = vb; v[ixj] = va;
                    idx[t] = ib; idx[ixj] = ia;
                }
            }
            __syncthreads();
        }
    }
    if (t < KP) tk[g * KP + t] = g * NPG + idx[t];
}

// ---------------------------------------------------------------------------
// 1D conv over sorted rows + relu. block = 32*26 = 832 threads, grid = B.
// ---------------------------------------------------------------------------
__global__ __launch_bounds__(832) void conv_pool(const float* __restrict__ x,
                                                 const int* __restrict__ tk,
                                                 const float* __restrict__ convW,
                                                 const float* __restrict__ convb,
                                                 float* __restrict__ cbuf) {
    __shared__ float xs[KP][HD];
    int b = blockIdx.x, t = threadIdx.x;
    for (int l = t; l < KP * HD; l += 832) {
        int r = l >> 7, c = l & 127;
        xs[r][c] = x[(size_t)tk[b * KP + r] * HD + c];
    }
    __syncthreads();
    int o = t / CT, tt = t % CT;
    float acc = convb[o];
    for (int kk = 0; kk < 5; ++kk)
        #pragma unroll 8
        for (int i = 0; i < HD; ++i)
            acc += xs[tt + kk][i] * convW[(o * HD + i) * 5 + kk];
    cbuf[b * FEAT + o * CT + tt] = acc > 0.f ? acc : 0.f;
}

// ---------------------------------------------------------------------------
// Head
// ---------------------------------------------------------------------------
__global__ __launch_bounds__(128) void lin1_k(const float* __restrict__ cbuf,
                                              const float* __restrict__ W,
                                              const float* __restrict__ bias,
                                              float* __restrict__ out1) {
    int b = blockIdx.x, c = threadIdx.x;
    const float* sc = cbuf + (size_t)b * FEAT;
    const float* fc = cbuf + (size_t)NB * FEAT + (size_t)b * FEAT;
    float acc = bias[c];
    for (int r = 0; r < FEAT; ++r) acc += sc[r] * W[r * HD + c];
    for (int r = 0; r < FEAT; ++r) acc += fc[r] * W[(FEAT + r) * HD + c];
    out1[b * HD + c] = acc > 0.f ? acc : 0.f;
}

__global__ __launch_bounds__(64) void lin2_k(const float* __restrict__ out1,
                                             const float* __restrict__ W2,
                                             const float* __restrict__ b2,
                                             float* __restrict__ out2) {
    int b = blockIdx.x, c = threadIdx.x;
    float acc = b2[c];
    for (int r = 0; r < HD; ++r) acc += out1[b * HD + r] * W2[r * 64 + c];
    out2[b * 64 + c] = acc > 0.f ? acc : 0.f;
}

__global__ __launch_bounds__(128) void lin3_k(const float* __restrict__ out2,
                                              const float* __restrict__ W3,
                                              const float* __restrict__ b3,
                                              float* __restrict__ x3) {
    int t = threadIdx.x;          // 128 threads: b = t>>1, c = t&1
    int b = t >> 1, c = t & 1;
    float acc = b3[c];
    for (int r = 0; r < 64; ++r) acc += out2[b * 64 + r] * W3[r * 2 + c];
    x3[t] = acc;
}

__global__ __launch_bounds__(64) void norm_k(const float* __restrict__ cbuf,
                                             float* __restrict__ inv_norm) {
    int i = blockIdx.x;            // 0..127 (64 sc rows then 64 fc rows)
    int t = threadIdx.x;
    const float* row = cbuf + (size_t)i * FEAT;
    float s = 0.f;
    for (int r = t; r < FEAT; r += 64) s += row[r] * row[r];
    #pragma unroll
    for (int o = 32; o; o >>= 1) s += __shfl_down(s, o);
    if (t == 0) inv_norm[i] = rsqrtf(s);
}

// grid (64, 2): blockIdx.x = i, blockIdx.y = branch (0: sc rows, 1: fc rows)
__global__ __launch_bounds__(64) void clip_k(const float* __restrict__ cbuf,
                                             const float* __restrict__ inv_norm,
                                             float* __restrict__ loss) {
    int i = blockIdx.x;
    int br = blockIdx.y;
    int j = threadIdx.x;
    const float* A  = cbuf + (br ? (size_t)NB * FEAT : 0);
    const float* Bm = cbuf + (br ? 0 : (size_t)NB * FEAT);
    const float* invA = inv_norm + (br ? 64 : 0);
    const float* invB = inv_norm + (br ? 0 : 64);
    const float* ai = A + (size_t)i * FEAT;
    float dp = 0.f, dng = 0.f;
    for (int r = 0; r < FEAT; ++r) {
        float a = ai[r];
        dp  += a * Bm[(size_t)j * FEAT + r];
        dng += a * A[(size_t)j * FEAT + r];
    }
    float lp = dp * invA[i] * invB[j] * 2.0f;                       // /TEMP
    float ln = (j == i) ? 0.0f : 0.8f * dng * invA[i] * invA[j] * 2.0f;
    float m = fmaxf(lp, ln);
    #pragma unroll
    for (int o = 32; o; o >>= 1) m = fmaxf(m, __shfl_xor(m, o));
    float s = expf(lp - m) + expf(ln - m);
    #pragma unroll
    for (int o = 32; o; o >>= 1) s += __shfl_xor(s, o);
    float lse = m + logf(s);
    float lpi = __shfl(lp, i);
    if (j == 0) atomicAdd(loss, (lse - lpi) * (1.0f / 128.0f));
}

__global__ __launch_bounds__(64) void final_k(const float* __restrict__ x3,
                                              const float* __restrict__ loss,
                                              float* __restrict__ out) {
    int b = threadIdx.x;
    float l0 = x3[b * 2], l1 = x3[b * 2 + 1];
    float m = fmaxf(l0, l1);
    float lse = m + logf(expf(l0 - m) + expf(l1 - m));
    float L = *loss;
    out[b * 2]     = l0 - lse + L;
    out[b * 2 + 1] = l1 - lse + L;
}

// ---------------------------------------------------------------------------
extern "C" void kernel_launch(void* const* d_in, const int* in_sizes, int n_in,
                              void* d_out, int out_size, void* d_ws, size_t ws_size,
                              hipStream_t stream) {
    (void)in_sizes; (void)n_in; (void)out_size; (void)ws_size;

    char* w = (char*)d_ws;
    auto alloc = [&](size_t bytes) -> char* {
        char* p = w;
        w += (bytes + 255) & ~(size_t)255;
        return p;
    };

    int*   counts  = (int*)  alloc((size_t)NN * 4);
    int*   offs    = (int*)  alloc((size_t)(NN + 1) * 4);
    int*   cursor  = (int*)  alloc((size_t)NN * 4);
    int*   csr_src = (int*)  alloc((size_t)NE * 4);
    float* dis     = (float*)alloc((size_t)NN * 4);
    float* xw      = (float*)alloc((size_t)NN * HD * 4);
    float* buf0    = (float*)alloc((size_t)NN * HD * 4);
    float* buf1    = (float*)alloc((size_t)NN * HD * 4);
    int*   tk      = (int*)  alloc((size_t)NB * KP * 4);
    float* cbuf    = (float*)alloc((size_t)2 * NB * FEAT * 4);
    float* inv_nrm = (float*)alloc(128 * 4);
    float* out1    = (float*)alloc((size_t)NB * HD * 4);
    float* out2    = (float*)alloc((size_t)NB * 64 * 4);
    float* x3      = (float*)alloc((size_t)NB * 2 * 4);
    float* loss    = (float*)alloc(4);
    unsigned short* whiT = (unsigned short*)alloc((size_t)4 * HD * HD * 2);
    unsigned short* wloT = (unsigned short*)alloc((size_t)4 * HD * HD * 2);

    hipMemsetAsync(loss, 0, 4, stream);

    for (int br = 0; br < 2; ++br) {
        const float* x_in   = (const float*)d_in[br];          // sc_x / fc_x
        const int*   edges  = (const int*)  d_in[2 + br];      // edge_index
        const float* Ws     = (const float*)d_in[br ? 6 : 4];
        const float* bs     = (const float*)d_in[br ? 7 : 5];
        const float* convW  = (const float*)d_in[br ? 10 : 8];
        const float* convb  = (const float*)d_in[br ? 11 : 9];
        float* cb = cbuf + (size_t)br * NB * FEAT;

        // CSR build (once per branch)
        hipMemsetAsync(counts, 0, (size_t)NN * 4, stream);
        count_k<<<NE / 256, 256, 0, stream>>>(edges, counts);
        scan_k<<<1, 1024, 0, stream>>>(counts, offs, cursor);
        dis_k<<<NN / 256, 256, 0, stream>>>(counts, dis);
        fill_k<<<NE / 256, 256, 0, stream>>>(edges, cursor, csr_src);

        // weight split/transpose for MFMA
        wprep_k<<<(4 * HD * HD) / 256, 256, 0, stream>>>(Ws, whiT, wloT);

        // 4 GCN layers
        const float* cur = x_in;
        float* bufs[2] = {buf0, buf1};
        for (int l = 0; l < 4; ++l) {
            gemm_mfma<<<NN / 128, 256, 0, stream>>>(cur,
                whiT + (size_t)l * HD * HD, wloT + (size_t)l * HD * HD, xw);
            float* nxt = bufs[l & 1];
            agg_relu<<<NN / 2, 256, 0, stream>>>(xw, csr_src, offs, dis,
                                                 bs + (size_t)l * HD, nxt);
            cur = nxt;
        }

        // sort-pool + conv
        sort_pool_k<<<NB, 512, 0, stream>>>(cur, tk);
        conv_pool<<<NB, 832, 0, stream>>>(cur, tk, convW, convb, cb);
    }

    // head + CLIP loss
    norm_k<<<128, 64, 0, stream>>>(cbuf, inv_nrm);
    clip_k<<<dim3(64, 2), 64, 0, stream>>>(cbuf, inv_nrm, loss);

    lin1_k<<<NB, 128, 0, stream>>>(cbuf, (const float*)d_in[12], (const float*)d_in[13], out1);
    lin2_k<<<NB, 64, 0, stream>>>(out1, (const float*)d_in[14], (const float*)d_in[15], out2);
    lin3_k<<<1, 128, 0, stream>>>(out2, (const float*)d_in[16], (const float*)d_in[17], x3);

    final_k<<<1, 64, 0, stream>>>(x3, loss, (float*)d_out);
}

// Round 3
// 756.150 us; speedup vs baseline: 1.6919x; 1.6919x over previous
//
#include <hip/hip_runtime.h>
#include <hip/hip_bf16.h>
#include <math.h>

#define NB    64      // graphs
#define NPG   512     // nodes per graph
#define NN    (NB*NPG)   // 32768 nodes
#define NE    524288  // edges per branch
#define EPG   (NE/NB)    // 8192 edges per graph
#define HD    128     // hidden dim
#define KP    30      // sort-pool k
#define CT    26      // K-4 conv output length
#define CO    32      // conv out channels
#define FEAT  (CO*CT) // 832 branch feature size

typedef short v8s __attribute__((ext_vector_type(8)));
typedef float v4f __attribute__((ext_vector_type(4)));

__device__ __forceinline__ unsigned short f2bf_rne(float x) {
    union { float f; unsigned u; } a; a.f = x;
    return (unsigned short)((a.u + 0x7fffu + ((a.u >> 16) & 1u)) >> 16);
}
__device__ __forceinline__ float bf2f(unsigned short b) {
    union { float f; unsigned u; } a; a.u = ((unsigned)b) << 16; return a.f;
}

// ---------------------------------------------------------------------------
// CSR build
// ---------------------------------------------------------------------------
__global__ void count_k(const int* __restrict__ edges, int* __restrict__ counts) {
    int e = blockIdx.x * 256 + threadIdx.x;
    atomicAdd(&counts[edges[NE + e]], 1);
}

// Per-graph exclusive scan: 64 blocks x 512 threads. Base for graph g is g*EPG
// (equal edge counts per graph by construction).
__global__ __launch_bounds__(512) void scan_graph_k(const int* __restrict__ counts,
                                                    int* __restrict__ offs,
                                                    int* __restrict__ cursor) {
    __shared__ int wsum[8];
    int g = blockIdx.x, t = threadIdx.x;
    int v = counts[g * NPG + t];
    int x = v;
    #pragma unroll
    for (int o = 1; o < 64; o <<= 1) {
        int y = __shfl_up(x, o);
        if ((t & 63) >= o) x += y;
    }
    int wid = t >> 6;
    if ((t & 63) == 63) wsum[wid] = x;
    __syncthreads();
    if (t == 0) {
        int run = 0;
        #pragma unroll
        for (int i = 0; i < 8; ++i) { int c = wsum[i]; wsum[i] = run; run += c; }
    }
    __syncthreads();
    int excl = g * EPG + wsum[wid] + x - v;
    offs[g * NPG + t] = excl;
    cursor[g * NPG + t] = excl;
    if (g == NB - 1 && t == NPG - 1) offs[NN] = NE;
}

__global__ void fill_k(const int* __restrict__ edges, int* __restrict__ cursor,
                       int* __restrict__ csr_src) {
    int e = blockIdx.x * 256 + threadIdx.x;
    int d = edges[NE + e];
    int p = atomicAdd(&cursor[d], 1);
    csr_src[p] = edges[e];
}

__global__ void dis_k(const int* __restrict__ counts, float* __restrict__ dis) {
    int n = blockIdx.x * 256 + threadIdx.x;
    dis[n] = rsqrtf((float)counts[n] + 1.0f);
}

// ---------------------------------------------------------------------------
// Weight prep: split fp32 W[l][k][n] into bf16 hi/lo, stored TRANSPOSED:
// hiT[l][n][k], loT[l][n][k]
// ---------------------------------------------------------------------------
__global__ __launch_bounds__(256) void wprep_k(const float* __restrict__ W,
                                               unsigned short* __restrict__ hiT,
                                               unsigned short* __restrict__ loT) {
    int idx = blockIdx.x * 256 + threadIdx.x;       // 0..65535
    int l = idx >> 14, r = idx & 16383;
    int k = r >> 7, n = r & 127;
    float x = W[idx];
    unsigned short h = f2bf_rne(x);
    float rem = x - bf2f(h);
    unsigned short lo = f2bf_rne(rem);
    size_t o = ((size_t)l << 14) + n * HD + k;
    hiT[o] = h;
    loT[o] = lo;
}

// ---------------------------------------------------------------------------
// MFMA GEMM: C[M][128] = X[M][128] @ W[128][128], fp32 via split-bf16.
// grid = M/128 (=256), block = 256 (4 waves). Each wave owns a 64x64 quadrant.
// ---------------------------------------------------------------------------
__global__ __launch_bounds__(256) void gemm_mfma(const float* __restrict__ X,
                                                 const unsigned short* __restrict__ WhiT,
                                                 const unsigned short* __restrict__ WloT,
                                                 float* __restrict__ C) {
    __shared__ __align__(16) unsigned short Xhi[128 * HD];
    __shared__ __align__(16) unsigned short Xlo[128 * HD];
    __shared__ __align__(16) unsigned short Bhi[128 * HD];
    __shared__ __align__(16) unsigned short Blo[128 * HD];

    int t = threadIdx.x;
    size_t r0 = (size_t)blockIdx.x * 128;

    const float4* Xg = (const float4*)(X + r0 * HD);
    #pragma unroll
    for (int i = 0; i < 16; ++i) {
        int f = t + i * 256;            // 0..4095 float4 slots
        int row = f >> 5, c4 = f & 31;
        float4 v = Xg[f];
        unsigned short h0 = f2bf_rne(v.x), h1 = f2bf_rne(v.y),
                       h2 = f2bf_rne(v.z), h3 = f2bf_rne(v.w);
        unsigned short l0 = f2bf_rne(v.x - bf2f(h0)), l1 = f2bf_rne(v.y - bf2f(h1)),
                       l2 = f2bf_rne(v.z - bf2f(h2)), l3 = f2bf_rne(v.w - bf2f(h3));
        int sidx = (row * HD + c4 * 4) ^ ((row & 7) << 3);
        *(ushort4*)&Xhi[sidx] = make_ushort4(h0, h1, h2, h3);
        *(ushort4*)&Xlo[sidx] = make_ushort4(l0, l1, l2, l3);
    }
    const uint4* WhiG = (const uint4*)WhiT;
    const uint4* WloG = (const uint4*)WloT;
    #pragma unroll
    for (int i = 0; i < 8; ++i) {
        int f = t + i * 256;            // 0..2047 16B chunks
        int n = f >> 4, k8 = f & 15;
        int sidx = (n * HD + k8 * 8) ^ ((n & 7) << 3);
        *(uint4*)&Bhi[sidx] = WhiG[f];
        *(uint4*)&Blo[sidx] = WloG[f];
    }
    __syncthreads();

    int lane = t & 63, wv = t >> 6;
    int wr = (wv >> 1) * 64, wc = (wv & 1) * 64;
    int fr = lane & 15, fq = lane >> 4;

    v4f acc[4][4];
    #pragma unroll
    for (int m = 0; m < 4; ++m)
        #pragma unroll
        for (int n = 0; n < 4; ++n)
            acc[m][n] = (v4f){0.f, 0.f, 0.f, 0.f};

    #pragma unroll
    for (int kk = 0; kk < 4; ++kk) {
        int k0 = kk * 32 + fq * 8;
        v8s ahi[4], alo[4], bhi[4], blo[4];
        #pragma unroll
        for (int m = 0; m < 4; ++m) {
            int row = wr + m * 16 + fr;
            int sidx = (row * HD + k0) ^ ((row & 7) << 3);
            ahi[m] = *(const v8s*)&Xhi[sidx];
            alo[m] = *(const v8s*)&Xlo[sidx];
        }
        #pragma unroll
        for (int n = 0; n < 4; ++n) {
            int rowb = wc + n * 16 + fr;
            int sidx = (rowb * HD + k0) ^ ((rowb & 7) << 3);
            bhi[n] = *(const v8s*)&Bhi[sidx];
            blo[n] = *(const v8s*)&Blo[sidx];
        }
        #pragma unroll
        for (int m = 0; m < 4; ++m)
            #pragma unroll
            for (int n = 0; n < 4; ++n) {
                acc[m][n] = __builtin_amdgcn_mfma_f32_16x16x32_bf16(ahi[m], bhi[n], acc[m][n], 0, 0, 0);
                acc[m][n] = __builtin_amdgcn_mfma_f32_16x16x32_bf16(ahi[m], blo[n], acc[m][n], 0, 0, 0);
                acc[m][n] = __builtin_amdgcn_mfma_f32_16x16x32_bf16(alo[m], bhi[n], acc[m][n], 0, 0, 0);
            }
    }

    #pragma unroll
    for (int m = 0; m < 4; ++m)
        #pragma unroll
        for (int n = 0; n < 4; ++n)
            #pragma unroll
            for (int rg = 0; rg < 4; ++rg)
                C[(r0 + wr + m * 16 + fq * 4 + rg) * HD + wc + n * 16 + fr] = acc[m][n][rg];
}

// ---------------------------------------------------------------------------
// GCN aggregation via per-graph LDS staging.
// grid (4 chblocks, 64 graphs), block 512.
// xs[s][c] = dis[s]*xw[s][c] staged for the graph's 512 nodes x 32 channels;
// csr entries localized into LDS; all gathers are LDS reads.
// ---------------------------------------------------------------------------
__global__ __launch_bounds__(512) void agg_graph(const float* __restrict__ xw,
                                                 const int* __restrict__ csr_src,
                                                 const int* __restrict__ offs,
                                                 const float* __restrict__ dis,
                                                 const float* __restrict__ bias,
                                                 float* __restrict__ out) {
    __shared__ float xs[NPG][32];     // 64 KB (pre-scaled by dis[src])
    __shared__ int   es[EPG];         // 32 KB localized src indices
    __shared__ int   eo[NPG + 1];     // local edge offsets
    __shared__ float ds_l[NPG];       // dis of graph nodes

    int cb = blockIdx.x, g = blockIdx.y;
    int t = threadIdx.x;
    int nbase = g * NPG;
    int ebase = g * EPG;
    int c0 = cb * 32;

    for (int i = t; i < NPG * 8; i += 512) {        // 8 float4 per row
        int row = i >> 3, f4 = i & 7;
        float dsrc = dis[nbase + row];
        float4 v = *(const float4*)&xw[(size_t)(nbase + row) * HD + c0 + f4 * 4];
        v.x *= dsrc; v.y *= dsrc; v.z *= dsrc; v.w *= dsrc;
        *(float4*)&xs[row][f4 * 4] = v;
    }
    for (int i = t; i < EPG; i += 512) es[i] = csr_src[ebase + i] - nbase;
    for (int i = t; i < NPG + 1; i += 512) eo[i] = offs[nbase + i] - ebase;
    for (int i = t; i < NPG; i += 512) ds_l[i] = dis[nbase + i];
    __syncthreads();

    int ch2 = (t & 15) * 2;
    float b0 = bias[c0 + ch2], b1 = bias[c0 + ch2 + 1];
    for (int n = t >> 4; n < NPG; n += 32) {
        float dn = ds_l[n];
        int e0 = eo[n], e1 = eo[n + 1];
        float ax = 0.f, ay = 0.f;
        for (int e = e0; e < e1; ++e) {
            int s = es[e];
            float2 xv = *(const float2*)&xs[s][ch2];
            ax += xv.x; ay += xv.y;
        }
        float2 sv = *(const float2*)&xs[n][ch2];
        float vx = dn * (ax + sv.x) + b0;
        float vy = dn * (ay + sv.y) + b1;
        float2 o2 = make_float2(vx > 0.f ? vx : 0.f, vy > 0.f ? vy : 0.f);
        *(float2*)&out[(size_t)(nbase + n) * HD + c0 + ch2] = o2;
    }
}

// ---------------------------------------------------------------------------
// sort_pool: per graph, bitonic sort 512 (value=ch127, idx) pairs,
// descending by value, ties -> lower index (matches jax.lax.top_k).
// ---------------------------------------------------------------------------
__global__ __launch_bounds__(512) void sort_pool_k(const float* __restrict__ x,
                                                   int* __restrict__ tk) {
    __shared__ float v[512];
    __shared__ int idx[512];
    int g = blockIdx.x, t = threadIdx.x;
    v[t] = x[(size_t)(g * NPG + t) * HD + (HD - 1)];
    idx[t] = t;
    __syncthreads();
    for (int k = 2; k <= 512; k <<= 1) {
        for (int j = k >> 1; j > 0; j >>= 1) {
            int ixj = t ^ j;
            if (ixj > t) {
                float va = v[t], vb = v[ixj];
                int ia = idx[t], ib = idx[ixj];
                bool aBefore = (va > vb) || (va == vb && ia < ib);
                bool dirDesc = ((t & k) == 0);
                if (dirDesc ? !aBefore : aBefore) {
                    v[t] = vb; v[ixj] = va;
                    idx[t] = ib; idx[ixj] = ia;
                }
            }
            __syncthreads();
        }
    }
    if (t < KP) tk[g * KP + t] = g * NPG + idx[t];
}

// ---------------------------------------------------------------------------
// 1D conv over sorted rows + relu. block = 32*26 = 832 threads, grid = B.
// ---------------------------------------------------------------------------
__global__ __launch_bounds__(832) void conv_pool(const float* __restrict__ x,
                                                 const int* __restrict__ tk,
                                                 const float* __restrict__ convW,
                                                 const float* __restrict__ convb,
                                                 float* __restrict__ cbuf) {
    __shared__ float xs[KP][HD];
    int b = blockIdx.x, t = threadIdx.x;
    for (int l = t; l < KP * HD; l += 832) {
        int r = l >> 7, c = l & 127;
        xs[r][c] = x[(size_t)tk[b * KP + r] * HD + c];
    }
    __syncthreads();
    int o = t / CT, tt = t % CT;
    float acc = convb[o];
    for (int kk = 0; kk < 5; ++kk)
        #pragma unroll 8
        for (int i = 0; i < HD; ++i)
            acc += xs[tt + kk][i] * convW[(o * HD + i) * 5 + kk];
    cbuf[b * FEAT + o * CT + tt] = acc > 0.f ? acc : 0.f;
}

// ---------------------------------------------------------------------------
// Head
// ---------------------------------------------------------------------------
__global__ __launch_bounds__(128) void lin1_k(const float* __restrict__ cbuf,
                                              const float* __restrict__ W,
                                              const float* __restrict__ bias,
                                              float* __restrict__ out1) {
    int b = blockIdx.x, c = threadIdx.x;
    const float* sc = cbuf + (size_t)b * FEAT;
    const float* fc = cbuf + (size_t)NB * FEAT + (size_t)b * FEAT;
    float acc = bias[c];
    for (int r = 0; r < FEAT; ++r) acc += sc[r] * W[r * HD + c];
    for (int r = 0; r < FEAT; ++r) acc += fc[r] * W[(FEAT + r) * HD + c];
    out1[b * HD + c] = acc > 0.f ? acc : 0.f;
}

__global__ __launch_bounds__(64) void lin2_k(const float* __restrict__ out1,
                                             const float* __restrict__ W2,
                                             const float* __restrict__ b2,
                                             float* __restrict__ out2) {
    int b = blockIdx.x, c = threadIdx.x;
    float acc = b2[c];
    for (int r = 0; r < HD; ++r) acc += out1[b * HD + r] * W2[r * 64 + c];
    out2[b * 64 + c] = acc > 0.f ? acc : 0.f;
}

__global__ __launch_bounds__(128) void lin3_k(const float* __restrict__ out2,
                                              const float* __restrict__ W3,
                                              const float* __restrict__ b3,
                                              float* __restrict__ x3) {
    int t = threadIdx.x;          // 128 threads: b = t>>1, c = t&1
    int b = t >> 1, c = t & 1;
    float acc = b3[c];
    for (int r = 0; r < 64; ++r) acc += out2[b * 64 + r] * W3[r * 2 + c];
    x3[t] = acc;
}

__global__ __launch_bounds__(64) void norm_k(const float* __restrict__ cbuf,
                                             float* __restrict__ inv_norm) {
    int i = blockIdx.x;            // 0..127 (64 sc rows then 64 fc rows)
    int t = threadIdx.x;
    const float* row = cbuf + (size_t)i * FEAT;
    float s = 0.f;
    for (int r = t; r < FEAT; r += 64) s += row[r] * row[r];
    #pragma unroll
    for (int o = 32; o; o >>= 1) s += __shfl_down(s, o);
    if (t == 0) inv_norm[i] = rsqrtf(s);
}

// grid (64, 2): blockIdx.x = i, blockIdx.y = branch (0: sc rows, 1: fc rows)
__global__ __launch_bounds__(64) void clip_k(const float* __restrict__ cbuf,
                                             const float* __restrict__ inv_norm,
                                             float* __restrict__ loss) {
    int i = blockIdx.x;
    int br = blockIdx.y;
    int j = threadIdx.x;
    const float* A  = cbuf + (br ? (size_t)NB * FEAT : 0);
    const float* Bm = cbuf + (br ? 0 : (size_t)NB * FEAT);
    const float* invA = inv_norm + (br ? 64 : 0);
    const float* invB = inv_norm + (br ? 0 : 64);
    const float* ai = A + (size_t)i * FEAT;
    float dp = 0.f, dng = 0.f;
    for (int r = 0; r < FEAT; ++r) {
        float a = ai[r];
        dp  += a * Bm[(size_t)j * FEAT + r];
        dng += a * A[(size_t)j * FEAT + r];
    }
    float lp = dp * invA[i] * invB[j] * 2.0f;                       // /TEMP
    float ln = (j == i) ? 0.0f : 0.8f * dng * invA[i] * invA[j] * 2.0f;
    float m = fmaxf(lp, ln);
    #pragma unroll
    for (int o = 32; o; o >>= 1) m = fmaxf(m, __shfl_xor(m, o));
    float s = expf(lp - m) + expf(ln - m);
    #pragma unroll
    for (int o = 32; o; o >>= 1) s += __shfl_xor(s, o);
    float lse = m + logf(s);
    float lpi = __shfl(lp, i);
    if (j == 0) atomicAdd(loss, (lse - lpi) * (1.0f / 128.0f));
}

__global__ __launch_bounds__(64) void final_k(const float* __restrict__ x3,
                                              const float* __restrict__ loss,
                                              float* __restrict__ out) {
    int b = threadIdx.x;
    float l0 = x3[b * 2], l1 = x3[b * 2 + 1];
    float m = fmaxf(l0, l1);
    float lse = m + logf(expf(l0 - m) + expf(l1 - m));
    float L = *loss;
    out[b * 2]     = l0 - lse + L;
    out[b * 2 + 1] = l1 - lse + L;
}

// ---------------------------------------------------------------------------
extern "C" void kernel_launch(void* const* d_in, const int* in_sizes, int n_in,
                              void* d_out, int out_size, void* d_ws, size_t ws_size,
                              hipStream_t stream) {
    (void)in_sizes; (void)n_in; (void)out_size; (void)ws_size;

    char* w = (char*)d_ws;
    auto alloc = [&](size_t bytes) -> char* {
        char* p = w;
        w += (bytes + 255) & ~(size_t)255;
        return p;
    };

    int*   counts  = (int*)  alloc((size_t)NN * 4);
    int*   offs    = (int*)  alloc((size_t)(NN + 1) * 4);
    int*   cursor  = (int*)  alloc((size_t)NN * 4);
    int*   csr_src = (int*)  alloc((size_t)NE * 4);
    float* dis     = (float*)alloc((size_t)NN * 4);
    float* xw      = (float*)alloc((size_t)NN * HD * 4);
    float* buf0    = (float*)alloc((size_t)NN * HD * 4);
    float* buf1    = (float*)alloc((size_t)NN * HD * 4);
    int*   tk      = (int*)  alloc((size_t)NB * KP * 4);
    float* cbuf    = (float*)alloc((size_t)2 * NB * FEAT * 4);
    float* inv_nrm = (float*)alloc(128 * 4);
    float* out1    = (float*)alloc((size_t)NB * HD * 4);
    float* out2    = (float*)alloc((size_t)NB * 64 * 4);
    float* x3      = (float*)alloc((size_t)NB * 2 * 4);
    float* loss    = (float*)alloc(4);
    unsigned short* whiT = (unsigned short*)alloc((size_t)4 * HD * HD * 2);
    unsigned short* wloT = (unsigned short*)alloc((size_t)4 * HD * HD * 2);

    hipMemsetAsync(loss, 0, 4, stream);

    for (int br = 0; br < 2; ++br) {
        const float* x_in   = (const float*)d_in[br];          // sc_x / fc_x
        const int*   edges  = (const int*)  d_in[2 + br];      // edge_index
        const float* Ws     = (const float*)d_in[br ? 6 : 4];
        const float* bs     = (const float*)d_in[br ? 7 : 5];
        const float* convW  = (const float*)d_in[br ? 10 : 8];
        const float* convb  = (const float*)d_in[br ? 11 : 9];
        float* cb = cbuf + (size_t)br * NB * FEAT;

        // CSR build (once per branch)
        hipMemsetAsync(counts, 0, (size_t)NN * 4, stream);
        count_k<<<NE / 256, 256, 0, stream>>>(edges, counts);
        scan_graph_k<<<NB, 512, 0, stream>>>(counts, offs, cursor);
        dis_k<<<NN / 256, 256, 0, stream>>>(counts, dis);
        fill_k<<<NE / 256, 256, 0, stream>>>(edges, cursor, csr_src);

        // weight split/transpose for MFMA
        wprep_k<<<(4 * HD * HD) / 256, 256, 0, stream>>>(Ws, whiT, wloT);

        // 4 GCN layers
        const float* cur = x_in;
        float* bufs[2] = {buf0, buf1};
        for (int l = 0; l < 4; ++l) {
            gemm_mfma<<<NN / 128, 256, 0, stream>>>(cur,
                whiT + (size_t)l * HD * HD, wloT + (size_t)l * HD * HD, xw);
            float* nxt = bufs[l & 1];
            agg_graph<<<dim3(4, NB), 512, 0, stream>>>(xw, csr_src, offs, dis,
                                                       bs + (size_t)l * HD, nxt);
            cur = nxt;
        }

        // sort-pool + conv
        sort_pool_k<<<NB, 512, 0, stream>>>(cur, tk);
        conv_pool<<<NB, 832, 0, stream>>>(cur, tk, convW, convb, cb);
    }

    // head + CLIP loss
    norm_k<<<128, 64, 0, stream>>>(cbuf, inv_nrm);
    clip_k<<<dim3(64, 2), 64, 0, stream>>>(cbuf, inv_nrm, loss);

    lin1_k<<<NB, 128, 0, stream>>>(cbuf, (const float*)d_in[12], (const float*)d_in[13], out1);
    lin2_k<<<NB, 64, 0, stream>>>(out1, (const float*)d_in[14], (const float*)d_in[15], out2);
    lin3_k<<<1, 128, 0, stream>>>(out2, (const float*)d_in[16], (const float*)d_in[17], x3);

    final_k<<<1, 64, 0, stream>>>(x3, loss, (float*)d_out);
}

// Round 4
// 667.277 us; speedup vs baseline: 1.9173x; 1.1332x over previous
//
#include <hip/hip_runtime.h>
#include <hip/hip_bf16.h>
#include <math.h>

#define NB    64      // graphs
#define NPG   512     // nodes per graph
#define NN    (NB*NPG)   // 32768 nodes
#define NE    524288  // edges per branch
#define EPG   (NE/NB)    // 8192 edges per graph
#define HD    128     // hidden dim
#define KP    30      // sort-pool k
#define CT    26      // K-4 conv output length
#define CO    32      // conv out channels
#define FEAT  (CO*CT) // 832 branch feature size
#define CPAD  132     // conv LDS row stride (4 mod 32 banks, 16B-aligned rows)

typedef short v8s __attribute__((ext_vector_type(8)));
typedef float v4f __attribute__((ext_vector_type(4)));

__device__ __forceinline__ unsigned short f2bf_rne(float x) {
    union { float f; unsigned u; } a; a.f = x;
    return (unsigned short)((a.u + 0x7fffu + ((a.u >> 16) & 1u)) >> 16);
}
__device__ __forceinline__ float bf2f(unsigned short b) {
    union { float f; unsigned u; } a; a.u = ((unsigned)b) << 16; return a.f;
}

// ---------------------------------------------------------------------------
// CSR build
// ---------------------------------------------------------------------------
__global__ void count_k(const int* __restrict__ edges, int* __restrict__ counts) {
    int e = blockIdx.x * 256 + threadIdx.x;
    atomicAdd(&counts[edges[NE + e]], 1);
}

// Per-graph exclusive scan: 64 blocks x 512 threads. Base for graph g is g*EPG.
__global__ __launch_bounds__(512) void scan_graph_k(const int* __restrict__ counts,
                                                    int* __restrict__ offs,
                                                    int* __restrict__ cursor) {
    __shared__ int wsum[8];
    int g = blockIdx.x, t = threadIdx.x;
    int v = counts[g * NPG + t];
    int x = v;
    #pragma unroll
    for (int o = 1; o < 64; o <<= 1) {
        int y = __shfl_up(x, o);
        if ((t & 63) >= o) x += y;
    }
    int wid = t >> 6;
    if ((t & 63) == 63) wsum[wid] = x;
    __syncthreads();
    if (t == 0) {
        int run = 0;
        #pragma unroll
        for (int i = 0; i < 8; ++i) { int c = wsum[i]; wsum[i] = run; run += c; }
    }
    __syncthreads();
    int excl = g * EPG + wsum[wid] + x - v;
    offs[g * NPG + t] = excl;
    cursor[g * NPG + t] = excl;
    if (g == NB - 1 && t == NPG - 1) offs[NN] = NE;
}

__global__ void fill_k(const int* __restrict__ edges, int* __restrict__ cursor,
                       int* __restrict__ csr_src) {
    int e = blockIdx.x * 256 + threadIdx.x;
    int d = edges[NE + e];
    int p = atomicAdd(&cursor[d], 1);
    csr_src[p] = edges[e];
}

__global__ void dis_k(const int* __restrict__ counts, float* __restrict__ dis) {
    int n = blockIdx.x * 256 + threadIdx.x;
    dis[n] = rsqrtf((float)counts[n] + 1.0f);
}

// ---------------------------------------------------------------------------
// Weight prep: split fp32 W[l][k][n] into bf16 hi/lo, stored TRANSPOSED:
// hiT[l][n][k], loT[l][n][k]
// ---------------------------------------------------------------------------
__global__ __launch_bounds__(256) void wprep_k(const float* __restrict__ W,
                                               unsigned short* __restrict__ hiT,
                                               unsigned short* __restrict__ loT) {
    int idx = blockIdx.x * 256 + threadIdx.x;       // 0..65535
    int l = idx >> 14, r = idx & 16383;
    int k = r >> 7, n = r & 127;
    float x = W[idx];
    unsigned short h = f2bf_rne(x);
    float rem = x - bf2f(h);
    unsigned short lo = f2bf_rne(rem);
    size_t o = ((size_t)l << 14) + n * HD + k;
    hiT[o] = h;
    loT[o] = lo;
}

// ---------------------------------------------------------------------------
// MFMA GEMM: C[M][128] = X[M][128] @ W[128][128], fp32 via split-bf16.
// grid = M/128 (=256), block = 256 (4 waves). Each wave owns a 64x64 quadrant.
// ---------------------------------------------------------------------------
__global__ __launch_bounds__(256) void gemm_mfma(const float* __restrict__ X,
                                                 const unsigned short* __restrict__ WhiT,
                                                 const unsigned short* __restrict__ WloT,
                                                 float* __restrict__ C) {
    __shared__ __align__(16) unsigned short Xhi[128 * HD];
    __shared__ __align__(16) unsigned short Xlo[128 * HD];
    __shared__ __align__(16) unsigned short Bhi[128 * HD];
    __shared__ __align__(16) unsigned short Blo[128 * HD];

    int t = threadIdx.x;
    size_t r0 = (size_t)blockIdx.x * 128;

    const float4* Xg = (const float4*)(X + r0 * HD);
    #pragma unroll
    for (int i = 0; i < 16; ++i) {
        int f = t + i * 256;            // 0..4095 float4 slots
        int row = f >> 5, c4 = f & 31;
        float4 v = Xg[f];
        unsigned short h0 = f2bf_rne(v.x), h1 = f2bf_rne(v.y),
                       h2 = f2bf_rne(v.z), h3 = f2bf_rne(v.w);
        unsigned short l0 = f2bf_rne(v.x - bf2f(h0)), l1 = f2bf_rne(v.y - bf2f(h1)),
                       l2 = f2bf_rne(v.z - bf2f(h2)), l3 = f2bf_rne(v.w - bf2f(h3));
        int sidx = (row * HD + c4 * 4) ^ ((row & 7) << 3);
        *(ushort4*)&Xhi[sidx] = make_ushort4(h0, h1, h2, h3);
        *(ushort4*)&Xlo[sidx] = make_ushort4(l0, l1, l2, l3);
    }
    const uint4* WhiG = (const uint4*)WhiT;
    const uint4* WloG = (const uint4*)WloT;
    #pragma unroll
    for (int i = 0; i < 8; ++i) {
        int f = t + i * 256;            // 0..2047 16B chunks
        int n = f >> 4, k8 = f & 15;
        int sidx = (n * HD + k8 * 8) ^ ((n & 7) << 3);
        *(uint4*)&Bhi[sidx] = WhiG[f];
        *(uint4*)&Blo[sidx] = WloG[f];
    }
    __syncthreads();

    int lane = t & 63, wv = t >> 6;
    int wr = (wv >> 1) * 64, wc = (wv & 1) * 64;
    int fr = lane & 15, fq = lane >> 4;

    v4f acc[4][4];
    #pragma unroll
    for (int m = 0; m < 4; ++m)
        #pragma unroll
        for (int n = 0; n < 4; ++n)
            acc[m][n] = (v4f){0.f, 0.f, 0.f, 0.f};

    #pragma unroll
    for (int kk = 0; kk < 4; ++kk) {
        int k0 = kk * 32 + fq * 8;
        v8s ahi[4], alo[4], bhi[4], blo[4];
        #pragma unroll
        for (int m = 0; m < 4; ++m) {
            int row = wr + m * 16 + fr;
            int sidx = (row * HD + k0) ^ ((row & 7) << 3);
            ahi[m] = *(const v8s*)&Xhi[sidx];
            alo[m] = *(const v8s*)&Xlo[sidx];
        }
        #pragma unroll
        for (int n = 0; n < 4; ++n) {
            int rowb = wc + n * 16 + fr;
            int sidx = (rowb * HD + k0) ^ ((rowb & 7) << 3);
            bhi[n] = *(const v8s*)&Bhi[sidx];
            blo[n] = *(const v8s*)&Blo[sidx];
        }
        #pragma unroll
        for (int m = 0; m < 4; ++m)
            #pragma unroll
            for (int n = 0; n < 4; ++n) {
                acc[m][n] = __builtin_amdgcn_mfma_f32_16x16x32_bf16(ahi[m], bhi[n], acc[m][n], 0, 0, 0);
                acc[m][n] = __builtin_amdgcn_mfma_f32_16x16x32_bf16(ahi[m], blo[n], acc[m][n], 0, 0, 0);
                acc[m][n] = __builtin_amdgcn_mfma_f32_16x16x32_bf16(alo[m], bhi[n], acc[m][n], 0, 0, 0);
            }
    }

    #pragma unroll
    for (int m = 0; m < 4; ++m)
        #pragma unroll
        for (int n = 0; n < 4; ++n)
            #pragma unroll
            for (int rg = 0; rg < 4; ++rg)
                C[(r0 + wr + m * 16 + fq * 4 + rg) * HD + wc + n * 16 + fr] = acc[m][n][rg];
}

// ---------------------------------------------------------------------------
// GCN aggregation via per-graph LDS staging.
// grid (4 chblocks, 64 graphs), block 512.
// ---------------------------------------------------------------------------
__global__ __launch_bounds__(512) void agg_graph(const float* __restrict__ xw,
                                                 const int* __restrict__ csr_src,
                                                 const int* __restrict__ offs,
                                                 const float* __restrict__ dis,
                                                 const float* __restrict__ bias,
                                                 float* __restrict__ out) {
    __shared__ float xs[NPG][32];     // 64 KB (pre-scaled by dis[src])
    __shared__ int   es[EPG];         // 32 KB localized src indices
    __shared__ int   eo[NPG + 1];     // local edge offsets
    __shared__ float ds_l[NPG];       // dis of graph nodes

    int cb = blockIdx.x, g = blockIdx.y;
    int t = threadIdx.x;
    int nbase = g * NPG;
    int ebase = g * EPG;
    int c0 = cb * 32;

    for (int i = t; i < NPG * 8; i += 512) {        // 8 float4 per row
        int row = i >> 3, f4 = i & 7;
        float dsrc = dis[nbase + row];
        float4 v = *(const float4*)&xw[(size_t)(nbase + row) * HD + c0 + f4 * 4];
        v.x *= dsrc; v.y *= dsrc; v.z *= dsrc; v.w *= dsrc;
        *(float4*)&xs[row][f4 * 4] = v;
    }
    for (int i = t; i < EPG; i += 512) es[i] = csr_src[ebase + i] - nbase;
    for (int i = t; i < NPG + 1; i += 512) eo[i] = offs[nbase + i] - ebase;
    for (int i = t; i < NPG; i += 512) ds_l[i] = dis[nbase + i];
    __syncthreads();

    int ch2 = (t & 15) * 2;
    float b0 = bias[c0 + ch2], b1 = bias[c0 + ch2 + 1];
    for (int n = t >> 4; n < NPG; n += 32) {
        float dn = ds_l[n];
        int e0 = eo[n], e1 = eo[n + 1];
        float ax = 0.f, ay = 0.f;
        for (int e = e0; e < e1; ++e) {
            int s = es[e];
            float2 xv = *(const float2*)&xs[s][ch2];
            ax += xv.x; ay += xv.y;
        }
        float2 sv = *(const float2*)&xs[n][ch2];
        float vx = dn * (ax + sv.x) + b0;
        float vy = dn * (ay + sv.y) + b1;
        float2 o2 = make_float2(vx > 0.f ? vx : 0.f, vy > 0.f ? vy : 0.f);
        *(float2*)&out[(size_t)(nbase + n) * HD + c0 + ch2] = o2;
    }
}

// ---------------------------------------------------------------------------
// sort_pool: per graph, bitonic sort 512 (value=ch127, idx) pairs,
// descending by value, ties -> lower index (matches jax.lax.top_k).
// ---------------------------------------------------------------------------
__global__ __launch_bounds__(512) void sort_pool_k(const float* __restrict__ x,
                                                   int* __restrict__ tk) {
    __shared__ float v[512];
    __shared__ int idx[512];
    int g = blockIdx.x, t = threadIdx.x;
    v[t] = x[(size_t)(g * NPG + t) * HD + (HD - 1)];
    idx[t] = t;
    __syncthreads();
    for (int k = 2; k <= 512; k <<= 1) {
        for (int j = k >> 1; j > 0; j >>= 1) {
            int ixj = t ^ j;
            if (ixj > t) {
                float va = v[t], vb = v[ixj];
                int ia = idx[t], ib = idx[ixj];
                bool aBefore = (va > vb) || (va == vb && ia < ib);
                bool dirDesc = ((t & k) == 0);
                if (dirDesc ? !aBefore : aBefore) {
                    v[t] = vb; v[ixj] = va;
                    idx[t] = ib; idx[ixj] = ia;
                }
            }
            __syncthreads();
        }
    }
    if (t < KP) tk[g * KP + t] = g * NPG + idx[t];
}

// ---------------------------------------------------------------------------
// 1D conv over sorted rows + relu.
// grid (NB, 4): graph g, output-channel chunk q (8 channels each).
// block 256: thread = (o_local, tt) for first 208 threads.
// xs rows padded to CPAD=132 floats (4 mod 32 banks -> <=4-way conflict);
// W slice transposed into LDS so i is contiguous (float4 reads).
// ---------------------------------------------------------------------------
__global__ __launch_bounds__(256) void conv_pool(const float* __restrict__ x,
                                                 const int* __restrict__ tk,
                                                 const float* __restrict__ convW,
                                                 const float* __restrict__ convb,
                                                 float* __restrict__ cbuf) {
    __shared__ float xs[KP][CPAD];      // 15.8 KB
    __shared__ float wl[8][5][CPAD];    // 21.1 KB  wl[o][kk][i]
    int g = blockIdx.x, q = blockIdx.y;
    int t = threadIdx.x;

    for (int l = t; l < KP * (HD / 4); l += 256) {      // 960 float4
        int r = l >> 5, c4 = l & 31;
        float4 v = *(const float4*)&x[(size_t)tk[g * KP + r] * HD + c4 * 4];
        *(float4*)&xs[r][c4 * 4] = v;
    }
    for (int l = t; l < 8 * 5 * HD; l += 256) {          // 5120
        int o = l / (5 * HD), r = l % (5 * HD), kk = r / HD, i = r % HD;
        wl[o][kk][i] = convW[((q * 8 + o) * HD + i) * 5 + kk];
    }
    __syncthreads();

    if (t < 8 * CT) {
        int tt = t % CT, o2 = t / CT;
        int o = q * 8 + o2;
        float acc = convb[o];
        #pragma unroll
        for (int kk = 0; kk < 5; ++kk) {
            const float* xr = &xs[tt + kk][0];
            const float* wr = &wl[o2][kk][0];
            #pragma unroll 8
            for (int i4 = 0; i4 < HD / 4; ++i4) {
                float4 a = *(const float4*)&xr[i4 * 4];
                float4 w = *(const float4*)&wr[i4 * 4];
                acc += a.x * w.x + a.y * w.y + a.z * w.z + a.w * w.w;
            }
        }
        cbuf[g * FEAT + o * CT + tt] = acc > 0.f ? acc : 0.f;
    }
}

// ---------------------------------------------------------------------------
// Head
// ---------------------------------------------------------------------------
__global__ __launch_bounds__(128) void lin1_k(const float* __restrict__ cbuf,
                                              const float* __restrict__ W,
                                              const float* __restrict__ bias,
                                              float* __restrict__ out1) {
    int b = blockIdx.x, c = threadIdx.x;
    const float* sc = cbuf + (size_t)b * FEAT;
    const float* fc = cbuf + (size_t)NB * FEAT + (size_t)b * FEAT;
    float acc = bias[c];
    for (int r = 0; r < FEAT; ++r) acc += sc[r] * W[r * HD + c];
    for (int r = 0; r < FEAT; ++r) acc += fc[r] * W[(FEAT + r) * HD + c];
    out1[b * HD + c] = acc > 0.f ? acc : 0.f;
}

__global__ __launch_bounds__(64) void lin2_k(const float* __restrict__ out1,
                                             const float* __restrict__ W2,
                                             const float* __restrict__ b2,
                                             float* __restrict__ out2) {
    int b = blockIdx.x, c = threadIdx.x;
    float acc = b2[c];
    for (int r = 0; r < HD; ++r) acc += out1[b * HD + r] * W2[r * 64 + c];
    out2[b * 64 + c] = acc > 0.f ? acc : 0.f;
}

__global__ __launch_bounds__(128) void lin3_k(const float* __restrict__ out2,
                                              const float* __restrict__ W3,
                                              const float* __restrict__ b3,
                                              float* __restrict__ x3) {
    int t = threadIdx.x;          // 128 threads: b = t>>1, c = t&1
    int b = t >> 1, c = t & 1;
    float acc = b3[c];
    for (int r = 0; r < 64; ++r) acc += out2[b * 64 + r] * W3[r * 2 + c];
    x3[t] = acc;
}

__global__ __launch_bounds__(64) void norm_k(const float* __restrict__ cbuf,
                                             float* __restrict__ inv_norm) {
    int i = blockIdx.x;            // 0..127 (64 sc rows then 64 fc rows)
    int t = threadIdx.x;
    const float* row = cbuf + (size_t)i * FEAT;
    float s = 0.f;
    for (int r = t; r < FEAT; r += 64) s += row[r] * row[r];
    #pragma unroll
    for (int o = 32; o; o >>= 1) s += __shfl_down(s, o);
    if (t == 0) inv_norm[i] = rsqrtf(s);
}

// grid (64, 2): blockIdx.x = i, blockIdx.y = branch (0: sc rows, 1: fc rows)
__global__ __launch_bounds__(64) void clip_k(const float* __restrict__ cbuf,
                                             const float* __restrict__ inv_norm,
                                             float* __restrict__ loss) {
    int i = blockIdx.x;
    int br = blockIdx.y;
    int j = threadIdx.x;
    const float* A  = cbuf + (br ? (size_t)NB * FEAT : 0);
    const float* Bm = cbuf + (br ? 0 : (size_t)NB * FEAT);
    const float* invA = inv_norm + (br ? 64 : 0);
    const float* invB = inv_norm + (br ? 0 : 64);
    const float* ai = A + (size_t)i * FEAT;
    float dp = 0.f, dng = 0.f;
    for (int r = 0; r < FEAT; ++r) {
        float a = ai[r];
        dp  += a * Bm[(size_t)j * FEAT + r];
        dng += a * A[(size_t)j * FEAT + r];
    }
    float lp = dp * invA[i] * invB[j] * 2.0f;                       // /TEMP
    float ln = (j == i) ? 0.0f : 0.8f * dng * invA[i] * invA[j] * 2.0f;
    float m = fmaxf(lp, ln);
    #pragma unroll
    for (int o = 32; o; o >>= 1) m = fmaxf(m, __shfl_xor(m, o));
    float s = expf(lp - m) + expf(ln - m);
    #pragma unroll
    for (int o = 32; o; o >>= 1) s += __shfl_xor(s, o);
    float lse = m + logf(s);
    float lpi = __shfl(lp, i);
    if (j == 0) atomicAdd(loss, (lse - lpi) * (1.0f / 128.0f));
}

__global__ __launch_bounds__(64) void final_k(const float* __restrict__ x3,
                                              const float* __restrict__ loss,
                                              float* __restrict__ out) {
    int b = threadIdx.x;
    float l0 = x3[b * 2], l1 = x3[b * 2 + 1];
    float m = fmaxf(l0, l1);
    float lse = m + logf(expf(l0 - m) + expf(l1 - m));
    float L = *loss;
    out[b * 2]     = l0 - lse + L;
    out[b * 2 + 1] = l1 - lse + L;
}

// ---------------------------------------------------------------------------
extern "C" void kernel_launch(void* const* d_in, const int* in_sizes, int n_in,
                              void* d_out, int out_size, void* d_ws, size_t ws_size,
                              hipStream_t stream) {
    (void)in_sizes; (void)n_in; (void)out_size; (void)ws_size;

    char* w = (char*)d_ws;
    auto alloc = [&](size_t bytes) -> char* {
        char* p = w;
        w += (bytes + 255) & ~(size_t)255;
        return p;
    };

    int*   counts  = (int*)  alloc((size_t)NN * 4);
    int*   offs    = (int*)  alloc((size_t)(NN + 1) * 4);
    int*   cursor  = (int*)  alloc((size_t)NN * 4);
    int*   csr_src = (int*)  alloc((size_t)NE * 4);
    float* dis     = (float*)alloc((size_t)NN * 4);
    float* xw      = (float*)alloc((size_t)NN * HD * 4);
    float* buf0    = (float*)alloc((size_t)NN * HD * 4);
    float* buf1    = (float*)alloc((size_t)NN * HD * 4);
    int*   tk      = (int*)  alloc((size_t)NB * KP * 4);
    float* cbuf    = (float*)alloc((size_t)2 * NB * FEAT * 4);
    float* inv_nrm = (float*)alloc(128 * 4);
    float* out1    = (float*)alloc((size_t)NB * HD * 4);
    float* out2    = (float*)alloc((size_t)NB * 64 * 4);
    float* x3      = (float*)alloc((size_t)NB * 2 * 4);
    float* loss    = (float*)alloc(4);
    unsigned short* whiT = (unsigned short*)alloc((size_t)4 * HD * HD * 2);
    unsigned short* wloT = (unsigned short*)alloc((size_t)4 * HD * HD * 2);

    hipMemsetAsync(loss, 0, 4, stream);

    for (int br = 0; br < 2; ++br) {
        const float* x_in   = (const float*)d_in[br];          // sc_x / fc_x
        const int*   edges  = (const int*)  d_in[2 + br];      // edge_index
        const float* Ws     = (const float*)d_in[br ? 6 : 4];
        const float* bs     = (const float*)d_in[br ? 7 : 5];
        const float* convW  = (const float*)d_in[br ? 10 : 8];
        const float* convb  = (const float*)d_in[br ? 11 : 9];
        float* cb = cbuf + (size_t)br * NB * FEAT;

        // CSR build (once per branch)
        hipMemsetAsync(counts, 0, (size_t)NN * 4, stream);
        count_k<<<NE / 256, 256, 0, stream>>>(edges, counts);
        scan_graph_k<<<NB, 512, 0, stream>>>(counts, offs, cursor);
        dis_k<<<NN / 256, 256, 0, stream>>>(counts, dis);
        fill_k<<<NE / 256, 256, 0, stream>>>(edges, cursor, csr_src);

        // weight split/transpose for MFMA
        wprep_k<<<(4 * HD * HD) / 256, 256, 0, stream>>>(Ws, whiT, wloT);

        // 4 GCN layers
        const float* cur = x_in;
        float* bufs[2] = {buf0, buf1};
        for (int l = 0; l < 4; ++l) {
            gemm_mfma<<<NN / 128, 256, 0, stream>>>(cur,
                whiT + (size_t)l * HD * HD, wloT + (size_t)l * HD * HD, xw);
            float* nxt = bufs[l & 1];
            agg_graph<<<dim3(4, NB), 512, 0, stream>>>(xw, csr_src, offs, dis,
                                                       bs + (size_t)l * HD, nxt);
            cur = nxt;
        }

        // sort-pool + conv
        sort_pool_k<<<NB, 512, 0, stream>>>(cur, tk);
        conv_pool<<<dim3(NB, 4), 256, 0, stream>>>(cur, tk, convW, convb, cb);
    }

    // head + CLIP loss
    norm_k<<<128, 64, 0, stream>>>(cbuf, inv_nrm);
    clip_k<<<dim3(64, 2), 64, 0, stream>>>(cbuf, inv_nrm, loss);

    lin1_k<<<NB, 128, 0, stream>>>(cbuf, (const float*)d_in[12], (const float*)d_in[13], out1);
    lin2_k<<<NB, 64, 0, stream>>>(out1, (const float*)d_in[14], (const float*)d_in[15], out2);
    lin3_k<<<1, 128, 0, stream>>>(out2, (const float*)d_in[16], (const float*)d_in[17], x3);

    final_k<<<1, 64, 0, stream>>>(x3, loss, (float*)d_out);
}

// Round 6
// 624.662 us; speedup vs baseline: 2.0481x; 1.0682x over previous
//
#include <hip/hip_runtime.h>
#include <hip/hip_bf16.h>
#include <math.h>

#define NB    64      // graphs
#define NPG   512     // nodes per graph
#define NN    (NB*NPG)   // 32768 nodes
#define NE    524288  // edges per branch
#define EPG   (NE/NB)    // 8192 edges per graph
#define HD    128     // hidden dim
#define KP    30      // sort-pool k
#define CT    26      // K-4 conv output length
#define CO    32      // conv out channels
#define FEAT  (CO*CT) // 832 branch feature size
#define CPAD  132     // conv LDS row stride (4 mod 32 banks, 16B-aligned rows)
#define KCH   13      // lin1 K chunks (13*128 = 1664)

typedef short v8s __attribute__((ext_vector_type(8)));
typedef float v4f __attribute__((ext_vector_type(4)));

__device__ __forceinline__ unsigned short f2bf_rne(float x) {
    union { float f; unsigned u; } a; a.f = x;
    return (unsigned short)((a.u + 0x7fffu + ((a.u >> 16) & 1u)) >> 16);
}
__device__ __forceinline__ float bf2f(unsigned short b) {
    union { float f; unsigned u; } a; a.u = ((unsigned)b) << 16; return a.f;
}

// ---------------------------------------------------------------------------
// CSR build
// ---------------------------------------------------------------------------
__global__ void count_k(const int* __restrict__ edges, int* __restrict__ counts) {
    int e = blockIdx.x * 256 + threadIdx.x;
    atomicAdd(&counts[edges[NE + e]], 1);
}

// Per-graph exclusive scan: 64 blocks x 512 threads. Base for graph g is g*EPG.
__global__ __launch_bounds__(512) void scan_graph_k(const int* __restrict__ counts,
                                                    int* __restrict__ offs,
                                                    int* __restrict__ cursor) {
    __shared__ int wsum[8];
    int g = blockIdx.x, t = threadIdx.x;
    int v = counts[g * NPG + t];
    int x = v;
    #pragma unroll
    for (int o = 1; o < 64; o <<= 1) {
        int y = __shfl_up(x, o);
        if ((t & 63) >= o) x += y;
    }
    int wid = t >> 6;
    if ((t & 63) == 63) wsum[wid] = x;
    __syncthreads();
    if (t == 0) {
        int run = 0;
        #pragma unroll
        for (int i = 0; i < 8; ++i) { int c = wsum[i]; wsum[i] = run; run += c; }
    }
    __syncthreads();
    int excl = g * EPG + wsum[wid] + x - v;
    offs[g * NPG + t] = excl;
    cursor[g * NPG + t] = excl;
    if (g == NB - 1 && t == NPG - 1) offs[NN] = NE;
}

__global__ void fill_k(const int* __restrict__ edges, int* __restrict__ cursor,
                       int* __restrict__ csr_src) {
    int e = blockIdx.x * 256 + threadIdx.x;
    int d = edges[NE + e];
    int p = atomicAdd(&cursor[d], 1);
    csr_src[p] = edges[e];
}

__global__ void dis_k(const int* __restrict__ counts, float* __restrict__ dis) {
    int n = blockIdx.x * 256 + threadIdx.x;
    dis[n] = rsqrtf((float)counts[n] + 1.0f);
}

// ---------------------------------------------------------------------------
// Weight prep: split fp32 W[l][k][n] into bf16 hi/lo, stored TRANSPOSED:
// hiT[l][n][k], loT[l][n][k]
// ---------------------------------------------------------------------------
__global__ __launch_bounds__(256) void wprep_k(const float* __restrict__ W,
                                               unsigned short* __restrict__ hiT,
                                               unsigned short* __restrict__ loT) {
    int idx = blockIdx.x * 256 + threadIdx.x;       // 0..65535
    int l = idx >> 14, r = idx & 16383;
    int k = r >> 7, n = r & 127;
    float x = W[idx];
    unsigned short h = f2bf_rne(x);
    float rem = x - bf2f(h);
    unsigned short lo = f2bf_rne(rem);
    size_t o = ((size_t)l << 14) + n * HD + k;
    hiT[o] = h;
    loT[o] = lo;
}

// ---------------------------------------------------------------------------
// MFMA GEMM: C[M][128] = X[M][128] @ W[128][128], fp32 via split-bf16.
// grid = M/128 (=256), block = 256 (4 waves). Each wave owns a 64x64 quadrant.
// ---------------------------------------------------------------------------
__global__ __launch_bounds__(256) void gemm_mfma(const float* __restrict__ X,
                                                 const unsigned short* __restrict__ WhiT,
                                                 const unsigned short* __restrict__ WloT,
                                                 float* __restrict__ C) {
    __shared__ __align__(16) unsigned short Xhi[128 * HD];
    __shared__ __align__(16) unsigned short Xlo[128 * HD];
    __shared__ __align__(16) unsigned short Bhi[128 * HD];
    __shared__ __align__(16) unsigned short Blo[128 * HD];

    int t = threadIdx.x;
    size_t r0 = (size_t)blockIdx.x * 128;

    const float4* Xg = (const float4*)(X + r0 * HD);
    #pragma unroll
    for (int i = 0; i < 16; ++i) {
        int f = t + i * 256;            // 0..4095 float4 slots
        int row = f >> 5, c4 = f & 31;
        float4 v = Xg[f];
        unsigned short h0 = f2bf_rne(v.x), h1 = f2bf_rne(v.y),
                       h2 = f2bf_rne(v.z), h3 = f2bf_rne(v.w);
        unsigned short l0 = f2bf_rne(v.x - bf2f(h0)), l1 = f2bf_rne(v.y - bf2f(h1)),
                       l2 = f2bf_rne(v.z - bf2f(h2)), l3 = f2bf_rne(v.w - bf2f(h3));
        int sidx = (row * HD + c4 * 4) ^ ((row & 7) << 3);
        *(ushort4*)&Xhi[sidx] = make_ushort4(h0, h1, h2, h3);
        *(ushort4*)&Xlo[sidx] = make_ushort4(l0, l1, l2, l3);
    }
    const uint4* WhiG = (const uint4*)WhiT;
    const uint4* WloG = (const uint4*)WloT;
    #pragma unroll
    for (int i = 0; i < 8; ++i) {
        int f = t + i * 256;            // 0..2047 16B chunks
        int n = f >> 4, k8 = f & 15;
        int sidx = (n * HD + k8 * 8) ^ ((n & 7) << 3);
        *(uint4*)&Bhi[sidx] = WhiG[f];
        *(uint4*)&Blo[sidx] = WloG[f];
    }
    __syncthreads();

    int lane = t & 63, wv = t >> 6;
    int wr = (wv >> 1) * 64, wc = (wv & 1) * 64;
    int fr = lane & 15, fq = lane >> 4;

    v4f acc[4][4];
    #pragma unroll
    for (int m = 0; m < 4; ++m)
        #pragma unroll
        for (int n = 0; n < 4; ++n)
            acc[m][n] = (v4f){0.f, 0.f, 0.f, 0.f};

    #pragma unroll
    for (int kk = 0; kk < 4; ++kk) {
        int k0 = kk * 32 + fq * 8;
        v8s ahi[4], alo[4], bhi[4], blo[4];
        #pragma unroll
        for (int m = 0; m < 4; ++m) {
            int row = wr + m * 16 + fr;
            int sidx = (row * HD + k0) ^ ((row & 7) << 3);
            ahi[m] = *(const v8s*)&Xhi[sidx];
            alo[m] = *(const v8s*)&Xlo[sidx];
        }
        #pragma unroll
        for (int n = 0; n < 4; ++n) {
            int rowb = wc + n * 16 + fr;
            int sidx = (rowb * HD + k0) ^ ((rowb & 7) << 3);
            bhi[n] = *(const v8s*)&Bhi[sidx];
            blo[n] = *(const v8s*)&Blo[sidx];
        }
        #pragma unroll
        for (int m = 0; m < 4; ++m)
            #pragma unroll
            for (int n = 0; n < 4; ++n) {
                acc[m][n] = __builtin_amdgcn_mfma_f32_16x16x32_bf16(ahi[m], bhi[n], acc[m][n], 0, 0, 0);
                acc[m][n] = __builtin_amdgcn_mfma_f32_16x16x32_bf16(ahi[m], blo[n], acc[m][n], 0, 0, 0);
                acc[m][n] = __builtin_amdgcn_mfma_f32_16x16x32_bf16(alo[m], bhi[n], acc[m][n], 0, 0, 0);
            }
    }

    #pragma unroll
    for (int m = 0; m < 4; ++m)
        #pragma unroll
        for (int n = 0; n < 4; ++n)
            #pragma unroll
            for (int rg = 0; rg < 4; ++rg)
                C[(r0 + wr + m * 16 + fq * 4 + rg) * HD + wc + n * 16 + fr] = acc[m][n][rg];
}

// ---------------------------------------------------------------------------
// GCN aggregation via per-graph LDS staging.
// grid (4 chblocks, 64 graphs), block 512.
// ---------------------------------------------------------------------------
__global__ __launch_bounds__(512) void agg_graph(const float* __restrict__ xw,
                                                 const int* __restrict__ csr_src,
                                                 const int* __restrict__ offs,
                                                 const float* __restrict__ dis,
                                                 const float* __restrict__ bias,
                                                 float* __restrict__ out) {
    __shared__ float xs[NPG][32];     // 64 KB (pre-scaled by dis[src])
    __shared__ int   es[EPG];         // 32 KB localized src indices
    __shared__ int   eo[NPG + 1];     // local edge offsets
    __shared__ float ds_l[NPG];       // dis of graph nodes

    int cb = blockIdx.x, g = blockIdx.y;
    int t = threadIdx.x;
    int nbase = g * NPG;
    int ebase = g * EPG;
    int c0 = cb * 32;

    for (int i = t; i < NPG * 8; i += 512) {        // 8 float4 per row
        int row = i >> 3, f4 = i & 7;
        float dsrc = dis[nbase + row];
        float4 v = *(const float4*)&xw[(size_t)(nbase + row) * HD + c0 + f4 * 4];
        v.x *= dsrc; v.y *= dsrc; v.z *= dsrc; v.w *= dsrc;
        *(float4*)&xs[row][f4 * 4] = v;
    }
    for (int i = t; i < EPG; i += 512) es[i] = csr_src[ebase + i] - nbase;
    for (int i = t; i < NPG + 1; i += 512) eo[i] = offs[nbase + i] - ebase;
    for (int i = t; i < NPG; i += 512) ds_l[i] = dis[nbase + i];
    __syncthreads();

    int ch2 = (t & 15) * 2;
    float b0 = bias[c0 + ch2], b1 = bias[c0 + ch2 + 1];
    for (int n = t >> 4; n < NPG; n += 32) {
        float dn = ds_l[n];
        int e0 = eo[n], e1 = eo[n + 1];
        float ax = 0.f, ay = 0.f;
        for (int e = e0; e < e1; ++e) {
            int s = es[e];
            float2 xv = *(const float2*)&xs[s][ch2];
            ax += xv.x; ay += xv.y;
        }
        float2 sv = *(const float2*)&xs[n][ch2];
        float vx = dn * (ax + sv.x) + b0;
        float vy = dn * (ay + sv.y) + b1;
        float2 o2 = make_float2(vx > 0.f ? vx : 0.f, vy > 0.f ? vy : 0.f);
        *(float2*)&out[(size_t)(nbase + n) * HD + c0 + ch2] = o2;
    }
}

// ---------------------------------------------------------------------------
// sort_pool: per graph, bitonic sort 512 (value=ch127, idx) pairs,
// descending by value, ties -> lower index (matches jax.lax.top_k).
// ---------------------------------------------------------------------------
__global__ __launch_bounds__(512) void sort_pool_k(const float* __restrict__ x,
                                                   int* __restrict__ tk) {
    __shared__ float v[512];
    __shared__ int idx[512];
    int g = blockIdx.x, t = threadIdx.x;
    v[t] = x[(size_t)(g * NPG + t) * HD + (HD - 1)];
    idx[t] = t;
    __syncthreads();
    for (int k = 2; k <= 512; k <<= 1) {
        for (int j = k >> 1; j > 0; j >>= 1) {
            int ixj = t ^ j;
            if (ixj > t) {
                float va = v[t], vb = v[ixj];
                int ia = idx[t], ib = idx[ixj];
                bool aBefore = (va > vb) || (va == vb && ia < ib);
                bool dirDesc = ((t & k) == 0);
                if (dirDesc ? !aBefore : aBefore) {
                    v[t] = vb; v[ixj] = va;
                    idx[t] = ib; idx[ixj] = ia;
                }
            }
            __syncthreads();
        }
    }
    if (t < KP) tk[g * KP + t] = g * NPG + idx[t];
}

// ---------------------------------------------------------------------------
// 1D conv over sorted rows + relu.
// grid (NB, 4): graph g, output-channel chunk q (8 channels each).
// ---------------------------------------------------------------------------
__global__ __launch_bounds__(256) void conv_pool(const float* __restrict__ x,
                                                 const int* __restrict__ tk,
                                                 const float* __restrict__ convW,
                                                 const float* __restrict__ convb,
                                                 float* __restrict__ cbuf) {
    __shared__ float xs[KP][CPAD];      // 15.8 KB
    __shared__ float wl[8][5][CPAD];    // 21.1 KB  wl[o][kk][i]
    int g = blockIdx.x, q = blockIdx.y;
    int t = threadIdx.x;

    for (int l = t; l < KP * (HD / 4); l += 256) {      // 960 float4
        int r = l >> 5, c4 = l & 31;
        float4 v = *(const float4*)&x[(size_t)tk[g * KP + r] * HD + c4 * 4];
        *(float4*)&xs[r][c4 * 4] = v;
    }
    for (int l = t; l < 8 * 5 * HD; l += 256) {          // 5120
        int o = l / (5 * HD), r = l % (5 * HD), kk = r / HD, i = r % HD;
        wl[o][kk][i] = convW[((q * 8 + o) * HD + i) * 5 + kk];
    }
    __syncthreads();

    if (t < 8 * CT) {
        int tt = t % CT, o2 = t / CT;
        int o = q * 8 + o2;
        float acc = convb[o];
        #pragma unroll
        for (int kk = 0; kk < 5; ++kk) {
            const float* xr = &xs[tt + kk][0];
            const float* wr = &wl[o2][kk][0];
            #pragma unroll 8
            for (int i4 = 0; i4 < HD / 4; ++i4) {
                float4 a = *(const float4*)&xr[i4 * 4];
                float4 w = *(const float4*)&wr[i4 * 4];
                acc += a.x * w.x + a.y * w.y + a.z * w.z + a.w * w.w;
            }
        }
        cbuf[g * FEAT + o * CT + tt] = acc > 0.f ? acc : 0.f;
    }
}

// ---------------------------------------------------------------------------
// Head: lin1 split-K (grid 64 x 13), then reduce.
// ---------------------------------------------------------------------------
__global__ __launch_bounds__(128) void lin1_part(const float* __restrict__ cbuf,
                                                 const float* __restrict__ W,
                                                 float* __restrict__ out1p) {
    __shared__ float fs[128];
    int b = blockIdx.x, kc = blockIdx.y, t = threadIdx.x;
    int r0 = kc * 128;
    int r = r0 + t;
    fs[t] = (r < FEAT) ? cbuf[(size_t)b * FEAT + r]
                       : cbuf[(size_t)NB * FEAT + (size_t)b * FEAT + (r - FEAT)];
    __syncthreads();
    float acc = 0.f;
    #pragma unroll 8
    for (int rr = 0; rr < 128; ++rr)
        acc += fs[rr] * W[(size_t)(r0 + rr) * HD + t];
    out1p[((size_t)b * KCH + kc) * HD + t] = acc;
}

__global__ __launch_bounds__(128) void lin1_red(const float* __restrict__ out1p,
                                                const float* __restrict__ bias,
                                                float* __restrict__ out1) {
    int b = blockIdx.x, c = threadIdx.x;
    float acc = bias[c];
    #pragma unroll
    for (int kc = 0; kc < KCH; ++kc) acc += out1p[((size_t)b * KCH + kc) * HD + c];
    out1[b * HD + c] = acc > 0.f ? acc : 0.f;
}

__global__ __launch_bounds__(64) void lin2_k(const float* __restrict__ out1,
                                             const float* __restrict__ W2,
                                             const float* __restrict__ b2,
                                             float* __restrict__ out2) {
    int b = blockIdx.x, c = threadIdx.x;
    float acc = b2[c];
    for (int r = 0; r < HD; ++r) acc += out1[b * HD + r] * W2[r * 64 + c];
    out2[b * 64 + c] = acc > 0.f ? acc : 0.f;
}

__global__ __launch_bounds__(128) void lin3_k(const float* __restrict__ out2,
                                              const float* __restrict__ W3,
                                              const float* __restrict__ b3,
                                              float* __restrict__ x3) {
    int t = threadIdx.x;          // 128 threads: b = t>>1, c = t&1
    int b = t >> 1, c = t & 1;
    float acc = b3[c];
    for (int r = 0; r < 64; ++r) acc += out2[b * 64 + r] * W3[r * 2 + c];
    x3[t] = acc;
}

__global__ __launch_bounds__(64) void norm_k(const float* __restrict__ cbuf,
                                             float* __restrict__ inv_norm) {
    int i = blockIdx.x;            // 0..127 (64 sc rows then 64 fc rows)
    int t = threadIdx.x;
    const float* row = cbuf + (size_t)i * FEAT;
    float s = 0.f;
    for (int r = t; r < FEAT; r += 64) s += row[r] * row[r];
    #pragma unroll
    for (int o = 32; o; o >>= 1) s += __shfl_down(s, o);
    if (t == 0) inv_norm[i] = rsqrtf(s);
}

// grid (64, 2): blockIdx.x = i, blockIdx.y = branch. 512 threads:
// 8 K-chunks (104 elems) x 64 j. Partials LDS-reduced, wave 0 finishes.
__global__ __launch_bounds__(512) void clip_k(const float* __restrict__ cbuf,
                                              const float* __restrict__ inv_norm,
                                              float* __restrict__ loss) {
    __shared__ float ai_s[FEAT];
    __shared__ float dpS[8][64];
    __shared__ float dnS[8][64];
    int i = blockIdx.x, br = blockIdx.y;
    int t = threadIdx.x;
    const float* A  = cbuf + (br ? (size_t)NB * FEAT : 0);
    const float* Bm = cbuf + (br ? 0 : (size_t)NB * FEAT);
    const float* invA = inv_norm + (br ? 64 : 0);
    const float* invB = inv_norm + (br ? 0 : 64);
    for (int r = t; r < FEAT; r += 512) ai_s[r] = A[(size_t)i * FEAT + r];
    __syncthreads();
    int j = t & 63, rc = t >> 6;
    float dp = 0.f, dn = 0.f;
    #pragma unroll 8
    for (int r = rc * 104; r < rc * 104 + 104; ++r) {
        float a = ai_s[r];
        dp += a * Bm[(size_t)j * FEAT + r];
        dn += a * A[(size_t)j * FEAT + r];
    }
    dpS[rc][j] = dp; dnS[rc][j] = dn;
    __syncthreads();
    if (t < 64) {
        float dpt = 0.f, dnt = 0.f;
        #pragma unroll
        for (int c = 0; c < 8; ++c) { dpt += dpS[c][t]; dnt += dnS[c][t]; }
        float lp = dpt * invA[i] * invB[t] * 2.0f;                     // /TEMP
        float ln = (t == i) ? 0.0f : 0.8f * dnt * invA[i] * invA[t] * 2.0f;
        float m = fmaxf(lp, ln);
        #pragma unroll
        for (int o = 32; o; o >>= 1) m = fmaxf(m, __shfl_xor(m, o));
        float s = expf(lp - m) + expf(ln - m);
        #pragma unroll
        for (int o = 32; o; o >>= 1) s += __shfl_xor(s, o);
        float lse = m + logf(s);
        float lpi = __shfl(lp, i);
        if (t == 0) atomicAdd(loss, (lse - lpi) * (1.0f / 128.0f));
    }
}

__global__ __launch_bounds__(64) void final_k(const float* __restrict__ x3,
                                              const float* __restrict__ loss,
                                              float* __restrict__ out) {
    int b = threadIdx.x;
    float l0 = x3[b * 2], l1 = x3[b * 2 + 1];
    float m = fmaxf(l0, l1);
    float lse = m + logf(expf(l0 - m) + expf(l1 - m));
    float L = *loss;
    out[b * 2]     = l0 - lse + L;
    out[b * 2 + 1] = l1 - lse + L;
}

// ---------------------------------------------------------------------------
extern "C" void kernel_launch(void* const* d_in, const int* in_sizes, int n_in,
                              void* d_out, int out_size, void* d_ws, size_t ws_size,
                              hipStream_t stream) {
    (void)in_sizes; (void)n_in; (void)out_size; (void)ws_size;

    char* w = (char*)d_ws;
    auto alloc = [&](size_t bytes) -> char* {
        char* p = w;
        w += (bytes + 255) & ~(size_t)255;
        return p;
    };

    int*   counts  = (int*)  alloc((size_t)NN * 4);
    int*   offs    = (int*)  alloc((size_t)(NN + 1) * 4);
    int*   cursor  = (int*)  alloc((size_t)NN * 4);
    int*   csr_src = (int*)  alloc((size_t)NE * 4);
    float* dis     = (float*)alloc((size_t)NN * 4);
    float* xw      = (float*)alloc((size_t)NN * HD * 4);
    float* buf0    = (float*)alloc((size_t)NN * HD * 4);
    float* buf1    = (float*)alloc((size_t)NN * HD * 4);
    int*   tk      = (int*)  alloc((size_t)NB * KP * 4);
    float* cbuf    = (float*)alloc((size_t)2 * NB * FEAT * 4);
    float* inv_nrm = (float*)alloc(128 * 4);
    float* out1    = (float*)alloc((size_t)NB * HD * 4);
    float* out1p   = (float*)alloc((size_t)NB * KCH * HD * 4);
    float* out2    = (float*)alloc((size_t)NB * 64 * 4);
    float* x3      = (float*)alloc((size_t)NB * 2 * 4);
    float* loss    = (float*)alloc(4);
    unsigned short* whiT = (unsigned short*)alloc((size_t)4 * HD * HD * 2);
    unsigned short* wloT = (unsigned short*)alloc((size_t)4 * HD * HD * 2);

    hipMemsetAsync(loss, 0, 4, stream);

    for (int br = 0; br < 2; ++br) {
        const float* x_in   = (const float*)d_in[br];          // sc_x / fc_x
        const int*   edges  = (const int*)  d_in[2 + br];      // edge_index
        const float* Ws     = (const float*)d_in[br ? 6 : 4];
        const float* bs     = (const float*)d_in[br ? 7 : 5];
        const float* convW  = (const float*)d_in[br ? 10 : 8];
        const float* convb  = (const float*)d_in[br ? 11 : 9];
        float* cb = cbuf + (size_t)br * NB * FEAT;

        // CSR build (once per branch)
        hipMemsetAsync(counts, 0, (size_t)NN * 4, stream);
        count_k<<<NE / 256, 256, 0, stream>>>(edges, counts);
        scan_graph_k<<<NB, 512, 0, stream>>>(counts, offs, cursor);
        dis_k<<<NN / 256, 256, 0, stream>>>(counts, dis);
        fill_k<<<NE / 256, 256, 0, stream>>>(edges, cursor, csr_src);

        // weight split/transpose for MFMA
        wprep_k<<<(4 * HD * HD) / 256, 256, 0, stream>>>(Ws, whiT, wloT);

        // 4 GCN layers
        const float* cur = x_in;
        float* bufs[2] = {buf0, buf1};
        for (int l = 0; l < 4; ++l) {
            gemm_mfma<<<NN / 128, 256, 0, stream>>>(cur,
                whiT + (size_t)l * HD * HD, wloT + (size_t)l * HD * HD, xw);
            float* nxt = bufs[l & 1];
            agg_graph<<<dim3(4, NB), 512, 0, stream>>>(xw, csr_src, offs, dis,
                                                       bs + (size_t)l * HD, nxt);
            cur = nxt;
        }

        // sort-pool + conv
        sort_pool_k<<<NB, 512, 0, stream>>>(cur, tk);
        conv_pool<<<dim3(NB, 4), 256, 0, stream>>>(cur, tk, convW, convb, cb);
    }

    // head + CLIP loss
    norm_k<<<128, 64, 0, stream>>>(cbuf, inv_nrm);
    clip_k<<<dim3(64, 2), 512, 0, stream>>>(cbuf, inv_nrm, loss);

    lin1_part<<<dim3(NB, KCH), 128, 0, stream>>>(cbuf, (const float*)d_in[12], out1p);
    lin1_red<<<NB, 128, 0, stream>>>(out1p, (const float*)d_in[13], out1);
    lin2_k<<<NB, 64, 0, stream>>>(out1, (const float*)d_in[14], (const float*)d_in[15], out2);
    lin3_k<<<1, 128, 0, stream>>>(out2, (const float*)d_in[16], (const float*)d_in[17], x3);

    final_k<<<1, 64, 0, stream>>>(x3, loss, (float*)d_out);
}

// Round 8
// 530.106 us; speedup vs baseline: 2.4134x; 1.1784x over previous
//
#include <hip/hip_runtime.h>
#include <hip/hip_bf16.h>
#include <math.h>

#define NB    64      // graphs
#define NPG   512     // nodes per graph
#define NN    (NB*NPG)   // 32768 nodes
#define NE    524288  // edges per branch
#define EPG   (NE/NB)    // 8192 edges per graph
#define HD    128     // hidden dim
#define KP    30      // sort-pool k
#define CT    26      // K-4 conv output length
#define CO    32      // conv out channels
#define FEAT  (CO*CT) // 832 branch feature size
#define CPAD  132     // conv LDS row stride (4 mod 32 banks, 16B-aligned rows)
#define KCH   13      // lin1 K chunks (13*128 = 1664)

typedef short v8s __attribute__((ext_vector_type(8)));
typedef float v4f __attribute__((ext_vector_type(4)));

__device__ __forceinline__ unsigned short f2bf_rne(float x) {
    union { float f; unsigned u; } a; a.f = x;
    return (unsigned short)((a.u + 0x7fffu + ((a.u >> 16) & 1u)) >> 16);
}
__device__ __forceinline__ float bf2f(unsigned short b) {
    union { float f; unsigned u; } a; a.u = ((unsigned)b) << 16; return a.f;
}

// ---------------------------------------------------------------------------
// Fused CSR build: count (LDS atomics) + scan + dis + fill, both branches.
// grid 128 (g = bid&63, br = bid>>6), block 512.
// ---------------------------------------------------------------------------
__global__ __launch_bounds__(512) void csr_build(const int* __restrict__ eA,
                                                 const int* __restrict__ eB,
                                                 int* __restrict__ csr_src,
                                                 int* __restrict__ offs,
                                                 float* __restrict__ dis) {
    __shared__ int cnt[NPG];
    __shared__ int cur[NPG];
    __shared__ int wsum[8];
    int bid = blockIdx.x;
    int br = bid >> 6, g = bid & 63;
    const int* edges = br ? eB : eA;
    int*   csr    = csr_src + (size_t)br * NE;
    int*   offs_b = offs    + (size_t)br * (NN + 1);
    float* dis_b  = dis     + (size_t)br * NN;
    int t = threadIdx.x;
    int nbase = g * NPG, ebase = g * EPG;
    const int* src = edges + ebase;
    const int* dst = edges + NE + ebase;

    cnt[t] = 0;
    __syncthreads();
    for (int i = t; i < EPG; i += 512) atomicAdd(&cnt[dst[i] - nbase], 1);
    __syncthreads();

    int v = cnt[t];
    int x = v;
    #pragma unroll
    for (int o = 1; o < 64; o <<= 1) {
        int y = __shfl_up(x, o);
        if ((t & 63) >= o) x += y;
    }
    int wid = t >> 6;
    if ((t & 63) == 63) wsum[wid] = x;
    __syncthreads();
    if (t == 0) {
        int run = 0;
        #pragma unroll
        for (int i = 0; i < 8; ++i) { int c = wsum[i]; wsum[i] = run; run += c; }
    }
    __syncthreads();
    int excl = wsum[wid] + x - v;              // local exclusive prefix
    offs_b[nbase + t] = ebase + excl;
    cur[t] = excl;
    dis_b[nbase + t] = rsqrtf((float)v + 1.0f);
    if (g == NB - 1 && t == NPG - 1) offs_b[NN] = NE;
    __syncthreads();

    for (int i = t; i < EPG; i += 512) {
        int d = dst[i] - nbase;
        int p = atomicAdd(&cur[d], 1);
        csr[ebase + p] = src[i];
    }
}

// ---------------------------------------------------------------------------
// Weight prep, both branches: split fp32 W[br][l][k][n] -> bf16 hi/lo,
// stored transposed hiT[br][l][n][k]. grid 512 x 256.
// ---------------------------------------------------------------------------
__global__ __launch_bounds__(256) void wprep_k(const float* __restrict__ WA,
                                               const float* __restrict__ WB,
                                               unsigned short* __restrict__ hiT,
                                               unsigned short* __restrict__ loT) {
    int idx = blockIdx.x * 256 + threadIdx.x;       // 0..131071
    int br = idx >> 16, r2 = idx & 65535;
    int l = r2 >> 14, r = r2 & 16383;
    int k = r >> 7, n = r & 127;
    const float* W = br ? WB : WA;
    float x = W[r2];
    unsigned short h = f2bf_rne(x);
    float rem = x - bf2f(h);
    unsigned short lo = f2bf_rne(rem);
    size_t o = ((size_t)(br * 4 + l) << 14) + n * HD + k;
    hiT[o] = h;
    loT[o] = lo;
}

// ---------------------------------------------------------------------------
// MFMA GEMM, both branches: grid (NN/128, 2), block 256 (4 waves).
// C[br][M][128] = X_br[M][128] @ W[br][l][128][128], fp32 via split-bf16.
// ---------------------------------------------------------------------------
__global__ __launch_bounds__(256) void gemm_mfma(const float* __restrict__ X0,
                                                 const float* __restrict__ X1,
                                                 const unsigned short* __restrict__ WhiT,
                                                 const unsigned short* __restrict__ WloT,
                                                 float* __restrict__ C,
                                                 int layer) {
    __shared__ __align__(16) unsigned short Xhi[128 * HD];
    __shared__ __align__(16) unsigned short Xlo[128 * HD];
    __shared__ __align__(16) unsigned short Bhi[128 * HD];
    __shared__ __align__(16) unsigned short Blo[128 * HD];

    int t = threadIdx.x;
    int br = blockIdx.y;
    size_t r0 = (size_t)blockIdx.x * 128;
    const float* X = br ? X1 : X0;
    size_t woff = (size_t)(br * 4 + layer) << 14;
    float* Cb = C + (size_t)br * NN * HD;

    const float4* Xg = (const float4*)(X + r0 * HD);
    #pragma unroll
    for (int i = 0; i < 16; ++i) {
        int f = t + i * 256;            // 0..4095 float4 slots
        int row = f >> 5, c4 = f & 31;
        float4 v = Xg[f];
        unsigned short h0 = f2bf_rne(v.x), h1 = f2bf_rne(v.y),
                       h2 = f2bf_rne(v.z), h3 = f2bf_rne(v.w);
        unsigned short l0 = f2bf_rne(v.x - bf2f(h0)), l1 = f2bf_rne(v.y - bf2f(h1)),
                       l2 = f2bf_rne(v.z - bf2f(h2)), l3 = f2bf_rne(v.w - bf2f(h3));
        int sidx = (row * HD + c4 * 4) ^ ((row & 7) << 3);
        *(ushort4*)&Xhi[sidx] = make_ushort4(h0, h1, h2, h3);
        *(ushort4*)&Xlo[sidx] = make_ushort4(l0, l1, l2, l3);
    }
    const uint4* WhiG = (const uint4*)(WhiT + woff);
    const uint4* WloG = (const uint4*)(WloT + woff);
    #pragma unroll
    for (int i = 0; i < 8; ++i) {
        int f = t + i * 256;            // 0..2047 16B chunks
        int n = f >> 4, k8 = f & 15;
        int sidx = (n * HD + k8 * 8) ^ ((n & 7) << 3);
        *(uint4*)&Bhi[sidx] = WhiG[f];
        *(uint4*)&Blo[sidx] = WloG[f];
    }
    __syncthreads();

    int lane = t & 63, wv = t >> 6;
    int wr = (wv >> 1) * 64, wc = (wv & 1) * 64;
    int fr = lane & 15, fq = lane >> 4;

    v4f acc[4][4];
    #pragma unroll
    for (int m = 0; m < 4; ++m)
        #pragma unroll
        for (int n = 0; n < 4; ++n)
            acc[m][n] = (v4f){0.f, 0.f, 0.f, 0.f};

    #pragma unroll
    for (int kk = 0; kk < 4; ++kk) {
        int k0 = kk * 32 + fq * 8;
        v8s ahi[4], alo[4], bhi[4], blo[4];
        #pragma unroll
        for (int m = 0; m < 4; ++m) {
            int row = wr + m * 16 + fr;
            int sidx = (row * HD + k0) ^ ((row & 7) << 3);
            ahi[m] = *(const v8s*)&Xhi[sidx];
            alo[m] = *(const v8s*)&Xlo[sidx];
        }
        #pragma unroll
        for (int n = 0; n < 4; ++n) {
            int rowb = wc + n * 16 + fr;
            int sidx = (rowb * HD + k0) ^ ((rowb & 7) << 3);
            bhi[n] = *(const v8s*)&Bhi[sidx];
            blo[n] = *(const v8s*)&Blo[sidx];
        }
        #pragma unroll
        for (int m = 0; m < 4; ++m)
            #pragma unroll
            for (int n = 0; n < 4; ++n) {
                acc[m][n] = __builtin_amdgcn_mfma_f32_16x16x32_bf16(ahi[m], bhi[n], acc[m][n], 0, 0, 0);
                acc[m][n] = __builtin_amdgcn_mfma_f32_16x16x32_bf16(ahi[m], blo[n], acc[m][n], 0, 0, 0);
                acc[m][n] = __builtin_amdgcn_mfma_f32_16x16x32_bf16(alo[m], bhi[n], acc[m][n], 0, 0, 0);
            }
    }

    #pragma unroll
    for (int m = 0; m < 4; ++m)
        #pragma unroll
        for (int n = 0; n < 4; ++n)
            #pragma unroll
            for (int rg = 0; rg < 4; ++rg)
                Cb[(r0 + wr + m * 16 + fq * 4 + rg) * HD + wc + n * 16 + fr] = acc[m][n][rg];
}

// ---------------------------------------------------------------------------
// GCN aggregation via per-graph LDS staging, both branches.
// grid (4 chblocks, 64 graphs, 2 branches), block 512.
// ---------------------------------------------------------------------------
__global__ __launch_bounds__(512) void agg_graph(const float* __restrict__ xw,
                                                 const int* __restrict__ csr_src,
                                                 const int* __restrict__ offs,
                                                 const float* __restrict__ dis,
                                                 const float* __restrict__ bsA,
                                                 const float* __restrict__ bsB,
                                                 float* __restrict__ out,
                                                 int layer) {
    __shared__ float xs[NPG][32];     // 64 KB (pre-scaled by dis[src])
    __shared__ int   es[EPG];         // 32 KB localized src indices
    __shared__ int   eo[NPG + 1];     // local edge offsets
    __shared__ float ds_l[NPG];       // dis of graph nodes

    int cb = blockIdx.x, g = blockIdx.y, br = blockIdx.z;
    int t = threadIdx.x;
    const float* xw_b  = xw      + (size_t)br * NN * HD;
    const int*   csr_b = csr_src + (size_t)br * NE;
    const int*   off_b = offs    + (size_t)br * (NN + 1);
    const float* dis_b = dis     + (size_t)br * NN;
    const float* bias  = (br ? bsB : bsA) + (size_t)layer * HD;
    float*       out_b = out     + (size_t)br * NN * HD;
    int nbase = g * NPG;
    int ebase = g * EPG;
    int c0 = cb * 32;

    for (int i = t; i < NPG * 8; i += 512) {        // 8 float4 per row
        int row = i >> 3, f4 = i & 7;
        float dsrc = dis_b[nbase + row];
        float4 v = *(const float4*)&xw_b[(size_t)(nbase + row) * HD + c0 + f4 * 4];
        v.x *= dsrc; v.y *= dsrc; v.z *= dsrc; v.w *= dsrc;
        *(float4*)&xs[row][f4 * 4] = v;
    }
    for (int i = t; i < EPG; i += 512) es[i] = csr_b[ebase + i] - nbase;
    for (int i = t; i < NPG + 1; i += 512) eo[i] = off_b[nbase + i] - ebase;
    for (int i = t; i < NPG; i += 512) ds_l[i] = dis_b[nbase + i];
    __syncthreads();

    int ch2 = (t & 15) * 2;
    float b0 = bias[c0 + ch2], b1 = bias[c0 + ch2 + 1];
    for (int n = t >> 4; n < NPG; n += 32) {
        float dn = ds_l[n];
        int e0 = eo[n], e1 = eo[n + 1];
        float ax = 0.f, ay = 0.f;
        for (int e = e0; e < e1; ++e) {
            int s = es[e];
            float2 xv = *(const float2*)&xs[s][ch2];
            ax += xv.x; ay += xv.y;
        }
        float2 sv = *(const float2*)&xs[n][ch2];
        float vx = dn * (ax + sv.x) + b0;
        float vy = dn * (ay + sv.y) + b1;
        float2 o2 = make_float2(vx > 0.f ? vx : 0.f, vy > 0.f ? vy : 0.f);
        *(float2*)&out_b[(size_t)(nbase + n) * HD + c0 + ch2] = o2;
    }
}

// ---------------------------------------------------------------------------
// Fused sort_pool + conv1d + relu. grid (NB, 2 branches), block 512.
// Bitonic sort 512 (desc by ch127, ties->lower idx = jax top_k), then
// conv over the top-30 rows entirely from LDS.
// ---------------------------------------------------------------------------
__global__ __launch_bounds__(512) void sortconv_k(const float* __restrict__ x,
                                                  const float* __restrict__ cwA,
                                                  const float* __restrict__ cwB,
                                                  const float* __restrict__ cbA,
                                                  const float* __restrict__ cbB,
                                                  float* __restrict__ cbuf) {
    __shared__ float v[512];
    __shared__ int   idx[512];
    __shared__ float xs[KP][CPAD];      // 15.8 KB
    __shared__ float wl[CO][5][HD];     // 80 KB  wl[o][kk][i]
    int g = blockIdx.x, br = blockIdx.y, t = threadIdx.x;
    const float* xb = x + (size_t)br * NN * HD;
    const float* convW = br ? cwB : cwA;
    const float* convb = br ? cbB : cbA;
    float* cb = cbuf + (size_t)br * NB * FEAT;

    v[t] = xb[(size_t)(g * NPG + t) * HD + (HD - 1)];
    idx[t] = t;
    // stage conv weights while sorting (independent of v/idx)
    for (int l = t; l < CO * 5 * HD; l += 512) {
        int o = l / (5 * HD), r = l % (5 * HD), kk = r / HD, i = r % HD;
        wl[o][kk][i] = convW[(o * HD + i) * 5 + kk];
    }
    __syncthreads();
    for (int k = 2; k <= 512; k <<= 1) {
        for (int j = k >> 1; j > 0; j >>= 1) {
            int ixj = t ^ j;
            if (ixj > t) {
                float va = v[t], vb = v[ixj];
                int ia = idx[t], ib = idx[ixj];
                bool aBefore = (va > vb) || (va == vb && ia < ib);
                bool dirDesc = ((t & k) == 0);
                if (dirDesc ? !aBefore : aBefore) {
                    v[t] = vb; v[ixj] = va;
                    idx[t] = ib; idx[ixj] = ia;
                }
            }
            __syncthreads();
        }
    }
    // stage top-30 rows
    for (int l = t; l < KP * (HD / 4); l += 512) {      // 960 float4
        int r = l >> 5, c4 = l & 31;
        float4 vv = *(const float4*)&xb[(size_t)(g * NPG + idx[r]) * HD + c4 * 4];
        *(float4*)&xs[r][c4 * 4] = vv;
    }
    __syncthreads();
    // conv: 832 outputs, threads take j = t, t+512
    for (int j = t; j < CO * CT; j += 512) {
        int o = j / CT, tt = j % CT;
        float acc = convb[o];
        #pragma unroll
        for (int kk = 0; kk < 5; ++kk) {
            const float* xr = &xs[tt + kk][0];
            const float* wr = &wl[o][kk][0];
            #pragma unroll 8
            for (int i4 = 0; i4 < HD / 4; ++i4) {
                float4 a = *(const float4*)&xr[i4 * 4];
                float4 w = *(const float4*)&wr[i4 * 4];
                acc += a.x * w.x + a.y * w.y + a.z * w.z + a.w * w.w;
            }
        }
        cb[g * FEAT + j] = acc > 0.f ? acc : 0.f;
    }
}

// ---------------------------------------------------------------------------
// Head
// ---------------------------------------------------------------------------
__global__ __launch_bounds__(128) void lin1_part(const float* __restrict__ cbuf,
                                                 const float* __restrict__ W,
                                                 float* __restrict__ out1p) {
    __shared__ float fs[128];
    int b = blockIdx.x, kc = blockIdx.y, t = threadIdx.x;
    int r0 = kc * 128;
    int r = r0 + t;
    fs[t] = (r < FEAT) ? cbuf[(size_t)b * FEAT + r]
                       : cbuf[(size_t)NB * FEAT + (size_t)b * FEAT + (r - FEAT)];
    __syncthreads();
    float acc = 0.f;
    #pragma unroll 8
    for (int rr = 0; rr < 128; ++rr)
        acc += fs[rr] * W[(size_t)(r0 + rr) * HD + t];
    out1p[((size_t)b * KCH + kc) * HD + t] = acc;
}

// lin1_red + lin2 + lin3 + final log_softmax + loss add. grid NB, block 128.
__global__ __launch_bounds__(128) void tail_k(const float* __restrict__ out1p,
                                              const float* __restrict__ b1,
                                              const float* __restrict__ W2,
                                              const float* __restrict__ b2,
                                              const float* __restrict__ W3,
                                              const float* __restrict__ b3,
                                              const float* __restrict__ loss,
                                              float* __restrict__ out) {
    __shared__ float o1[HD];
    __shared__ float o2[64];
    __shared__ float x3s[2];
    int b = blockIdx.x, t = threadIdx.x;
    float acc = b1[t];
    #pragma unroll
    for (int kc = 0; kc < KCH; ++kc) acc += out1p[((size_t)b * KCH + kc) * HD + t];
    o1[t] = acc > 0.f ? acc : 0.f;
    __syncthreads();
    if (t < 64) {
        float a2 = b2[t];
        #pragma unroll 8
        for (int r = 0; r < HD; ++r) a2 += o1[r] * W2[r * 64 + t];
        o2[t] = a2 > 0.f ? a2 : 0.f;
    }
    __syncthreads();
    if (t < 2) {
        float a3 = b3[t];
        for (int r = 0; r < 64; ++r) a3 += o2[r] * W3[r * 2 + t];
        x3s[t] = a3;
    }
    __syncthreads();
    if (t == 0) {
        float l0 = x3s[0], l1 = x3s[1];
        float m = fmaxf(l0, l1);
        float lse = m + logf(expf(l0 - m) + expf(l1 - m));
        float L = *loss;
        out[b * 2]     = l0 - lse + L;
        out[b * 2 + 1] = l1 - lse + L;
    }
}

__global__ __launch_bounds__(64) void norm_k(const float* __restrict__ cbuf,
                                             float* __restrict__ inv_norm) {
    int i = blockIdx.x;            // 0..127 (64 sc rows then 64 fc rows)
    int t = threadIdx.x;
    const float* row = cbuf + (size_t)i * FEAT;
    float s = 0.f;
    for (int r = t; r < FEAT; r += 64) s += row[r] * row[r];
    #pragma unroll
    for (int o = 32; o; o >>= 1) s += __shfl_down(s, o);
    if (t == 0) inv_norm[i] = rsqrtf(s);
}

// grid (64, 2): blockIdx.x = i, blockIdx.y = branch. 512 threads:
// 8 K-chunks (104 elems) x 64 j. Partials LDS-reduced, wave 0 finishes.
__global__ __launch_bounds__(512) void clip_k(const float* __restrict__ cbuf,
                                              const float* __restrict__ inv_norm,
                                              float* __restrict__ loss) {
    __shared__ float ai_s[FEAT];
    __shared__ float dpS[8][64];
    __shared__ float dnS[8][64];
    int i = blockIdx.x, br = blockIdx.y;
    int t = threadIdx.x;
    const float* A  = cbuf + (br ? (size_t)NB * FEAT : 0);
    const float* Bm = cbuf + (br ? 0 : (size_t)NB * FEAT);
    const float* invA = inv_norm + (br ? 64 : 0);
    const float* invB = inv_norm + (br ? 0 : 64);
    for (int r = t; r < FEAT; r += 512) ai_s[r] = A[(size_t)i * FEAT + r];
    __syncthreads();
    int j = t & 63, rc = t >> 6;
    float dp = 0.f, dn = 0.f;
    #pragma unroll 8
    for (int r = rc * 104; r < rc * 104 + 104; ++r) {
        float a = ai_s[r];
        dp += a * Bm[(size_t)j * FEAT + r];
        dn += a * A[(size_t)j * FEAT + r];
    }
    dpS[rc][j] = dp; dnS[rc][j] = dn;
    __syncthreads();
    if (t < 64) {
        float dpt = 0.f, dnt = 0.f;
        #pragma unroll
        for (int c = 0; c < 8; ++c) { dpt += dpS[c][t]; dnt += dnS[c][t]; }
        float lp = dpt * invA[i] * invB[t] * 2.0f;                     // /TEMP
        float ln = (t == i) ? 0.0f : 0.8f * dnt * invA[i] * invA[t] * 2.0f;
        float m = fmaxf(lp, ln);
        #pragma unroll
        for (int o = 32; o; o >>= 1) m = fmaxf(m, __shfl_xor(m, o));
        float s = expf(lp - m) + expf(ln - m);
        #pragma unroll
        for (int o = 32; o; o >>= 1) s += __shfl_xor(s, o);
        float lse = m + logf(s);
        float lpi = __shfl(lp, i);
        if (t == 0) atomicAdd(loss, (lse - lpi) * (1.0f / 128.0f));
    }
}

// ---------------------------------------------------------------------------
extern "C" void kernel_launch(void* const* d_in, const int* in_sizes, int n_in,
                              void* d_out, int out_size, void* d_ws, size_t ws_size,
                              hipStream_t stream) {
    (void)in_sizes; (void)n_in; (void)out_size; (void)ws_size;

    char* w = (char*)d_ws;
    auto alloc = [&](size_t bytes) -> char* {
        char* p = w;
        w += (bytes + 255) & ~(size_t)255;
        return p;
    };

    int*   offs    = (int*)  alloc((size_t)2 * (NN + 1) * 4);
    int*   csr_src = (int*)  alloc((size_t)2 * NE * 4);
    float* dis     = (float*)alloc((size_t)2 * NN * 4);
    float* xw      = (float*)alloc((size_t)2 * NN * HD * 4);
    float* buf0    = (float*)alloc((size_t)2 * NN * HD * 4);
    float* buf1    = (float*)alloc((size_t)2 * NN * HD * 4);
    float* cbuf    = (float*)alloc((size_t)2 * NB * FEAT * 4);
    float* inv_nrm = (float*)alloc(128 * 4);
    float* out1p   = (float*)alloc((size_t)NB * KCH * HD * 4);
    float* loss    = (float*)alloc(4);
    unsigned short* whiT = (unsigned short*)alloc((size_t)2 * 4 * HD * HD * 2);
    unsigned short* wloT = (unsigned short*)alloc((size_t)2 * 4 * HD * HD * 2);

    hipMemsetAsync(loss, 0, 4, stream);

    const float* sc_x  = (const float*)d_in[0];
    const float* fc_x  = (const float*)d_in[1];
    const int*   edgeA = (const int*)  d_in[2];
    const int*   edgeB = (const int*)  d_in[3];
    const float* WsA   = (const float*)d_in[4];
    const float* bsA   = (const float*)d_in[5];
    const float* WsB   = (const float*)d_in[6];
    const float* bsB   = (const float*)d_in[7];
    const float* cwA   = (const float*)d_in[8];
    const float* cbA   = (const float*)d_in[9];
    const float* cwB   = (const float*)d_in[10];
    const float* cbB   = (const float*)d_in[11];

    csr_build<<<128, 512, 0, stream>>>(edgeA, edgeB, csr_src, offs, dis);
    wprep_k<<<512, 256, 0, stream>>>(WsA, WsB, whiT, wloT);

    // 4 GCN layers, both branches per dispatch
    const float* cur0 = sc_x;
    const float* cur1 = fc_x;
    float* bufs[2] = {buf0, buf1};
    for (int l = 0; l < 4; ++l) {
        gemm_mfma<<<dim3(NN / 128, 2), 256, 0, stream>>>(cur0, cur1, whiT, wloT, xw, l);
        float* nxt = bufs[l & 1];
        agg_graph<<<dim3(4, NB, 2), 512, 0, stream>>>(xw, csr_src, offs, dis,
                                                      bsA, bsB, nxt, l);
        cur0 = nxt;
        cur1 = nxt + (size_t)NN * HD;
    }

    // fused sort-pool + conv, both branches
    sortconv_k<<<dim3(NB, 2), 512, 0, stream>>>(cur0, cwA, cwB, cbA, cbB, cbuf);

    // head + CLIP loss
    norm_k<<<128, 64, 0, stream>>>(cbuf, inv_nrm);
    clip_k<<<dim3(64, 2), 512, 0, stream>>>(cbuf, inv_nrm, loss);

    lin1_part<<<dim3(NB, KCH), 128, 0, stream>>>(cbuf, (const float*)d_in[12], out1p);
    tail_k<<<NB, 128, 0, stream>>>(out1p, (const float*)d_in[13],
                                   (const float*)d_in[14], (const float*)d_in[15],
                                   (const float*)d_in[16], (const float*)d_in[17],
                                   loss, (float*)d_out);
}

// Round 11
// 460.888 us; speedup vs baseline: 2.7758x; 1.1502x over previous
//
#include <hip/hip_runtime.h>
#include <hip/hip_bf16.h>
#include <math.h>

#define NB    64      // graphs
#define NPG   512     // nodes per graph
#define NN    (NB*NPG)   // 32768 nodes
#define NE    524288  // edges per branch
#define EPG   (NE/NB)    // 8192 edges per graph
#define HD    128     // hidden dim
#define KP    30      // sort-pool k
#define CT    26      // K-4 conv output length
#define CO    32      // conv out channels
#define FEAT  (CO*CT) // 832 branch feature size
#define CPAD  132     // conv LDS row stride (4 mod 32 banks, 16B-aligned rows)
#define KCH   13      // lin1 K chunks (13*128 = 1664)

typedef short v8s __attribute__((ext_vector_type(8)));
typedef float v4f __attribute__((ext_vector_type(4)));

__device__ __forceinline__ unsigned short f2bf_rne(float x) {
    union { float f; unsigned u; } a; a.f = x;
    return (unsigned short)((a.u + 0x7fffu + ((a.u >> 16) & 1u)) >> 16);
}
__device__ __forceinline__ float bf2f(unsigned short b) {
    union { float f; unsigned u; } a; a.u = ((unsigned)b) << 16; return a.f;
}

// ---------------------------------------------------------------------------
// Fused CSR build: count (LDS atomics) + scan + dis + fill, both branches.
// grid 128 (g = bid&63, br = bid>>6), block 512.
// ---------------------------------------------------------------------------
__global__ __launch_bounds__(512) void csr_build(const int* __restrict__ eA,
                                                 const int* __restrict__ eB,
                                                 int* __restrict__ csr_src,
                                                 int* __restrict__ offs,
                                                 float* __restrict__ dis) {
    __shared__ int cnt[NPG];
    __shared__ int cur[NPG];
    __shared__ int wsum[8];
    int bid = blockIdx.x;
    int br = bid >> 6, g = bid & 63;
    const int* edges = br ? eB : eA;
    int*   csr    = csr_src + (size_t)br * NE;
    int*   offs_b = offs    + (size_t)br * (NN + 1);
    float* dis_b  = dis     + (size_t)br * NN;
    int t = threadIdx.x;
    int nbase = g * NPG, ebase = g * EPG;
    const int* src = edges + ebase;
    const int* dst = edges + NE + ebase;

    cnt[t] = 0;
    __syncthreads();
    for (int i = t; i < EPG; i += 512) atomicAdd(&cnt[dst[i] - nbase], 1);
    __syncthreads();

    int v = cnt[t];
    int x = v;
    #pragma unroll
    for (int o = 1; o < 64; o <<= 1) {
        int y = __shfl_up(x, o);
        if ((t & 63) >= o) x += y;
    }
    int wid = t >> 6;
    if ((t & 63) == 63) wsum[wid] = x;
    __syncthreads();
    if (t == 0) {
        int run = 0;
        #pragma unroll
        for (int i = 0; i < 8; ++i) { int c = wsum[i]; wsum[i] = run; run += c; }
    }
    __syncthreads();
    int excl = wsum[wid] + x - v;              // local exclusive prefix
    offs_b[nbase + t] = ebase + excl;
    cur[t] = excl;
    dis_b[nbase + t] = rsqrtf((float)v + 1.0f);
    if (g == NB - 1 && t == NPG - 1) offs_b[NN] = NE;
    __syncthreads();

    for (int i = t; i < EPG; i += 512) {
        int d = dst[i] - nbase;
        int p = atomicAdd(&cur[d], 1);
        csr[ebase + p] = src[i];
    }
}

// ---------------------------------------------------------------------------
// Weight prep via LDS-tile transpose: coalesced reads AND writes.
// grid 8 (bl = br*4+layer), block 1024.
// hiT[bl][n][k] = bf16_hi(W[bl][k][n]), loT likewise.
// ---------------------------------------------------------------------------
__global__ __launch_bounds__(1024) void wprep_k(const float* __restrict__ WA,
                                                const float* __restrict__ WB,
                                                unsigned short* __restrict__ hiT,
                                                unsigned short* __restrict__ loT) {
    __shared__ unsigned short hi[128][130];   // 130-pad: conflict-free transpose
    __shared__ unsigned short lo[128][130];
    int bl = blockIdx.x;
    const float* W = (bl >= 4 ? WB : WA) + ((size_t)(bl & 3) << 14);
    int t = threadIdx.x;
    for (int i = t; i < 16384; i += 1024) {       // read W[k][n] coalesced
        int k = i >> 7, n = i & 127;
        float x = W[i];
        unsigned short h = f2bf_rne(x);
        hi[n][k] = h;
        lo[n][k] = f2bf_rne(x - bf2f(h));
    }
    __syncthreads();
    size_t base = (size_t)bl << 14;
    for (int i = t; i < 16384; i += 1024) {       // write hiT[n][k] coalesced
        int n = i >> 7, k = i & 127;
        hiT[base + i] = hi[n][k];
        loT[base + i] = lo[n][k];
    }
}

// ---------------------------------------------------------------------------
// MFMA GEMM, both branches: grid (NN/128, 2), block 256 (4 waves).
// C[br][M][128] = X_br[M][128] @ W[br][l][128][128], fp32 via split-bf16.
// ---------------------------------------------------------------------------
__global__ __launch_bounds__(256) void gemm_mfma(const float* __restrict__ X0,
                                                 const float* __restrict__ X1,
                                                 const unsigned short* __restrict__ WhiT,
                                                 const unsigned short* __restrict__ WloT,
                                                 float* __restrict__ C,
                                                 int layer) {
    __shared__ __align__(16) unsigned short Xhi[128 * HD];
    __shared__ __align__(16) unsigned short Xlo[128 * HD];
    __shared__ __align__(16) unsigned short Bhi[128 * HD];
    __shared__ __align__(16) unsigned short Blo[128 * HD];

    int t = threadIdx.x;
    int br = blockIdx.y;
    size_t r0 = (size_t)blockIdx.x * 128;
    const float* X = br ? X1 : X0;
    size_t woff = (size_t)(br * 4 + layer) << 14;
    float* Cb = C + (size_t)br * NN * HD;

    const float4* Xg = (const float4*)(X + r0 * HD);
    #pragma unroll
    for (int i = 0; i < 16; ++i) {
        int f = t + i * 256;            // 0..4095 float4 slots
        int row = f >> 5, c4 = f & 31;
        float4 v = Xg[f];
        unsigned short h0 = f2bf_rne(v.x), h1 = f2bf_rne(v.y),
                       h2 = f2bf_rne(v.z), h3 = f2bf_rne(v.w);
        unsigned short l0 = f2bf_rne(v.x - bf2f(h0)), l1 = f2bf_rne(v.y - bf2f(h1)),
                       l2 = f2bf_rne(v.z - bf2f(h2)), l3 = f2bf_rne(v.w - bf2f(h3));
        int sidx = (row * HD + c4 * 4) ^ ((row & 7) << 3);
        *(ushort4*)&Xhi[sidx] = make_ushort4(h0, h1, h2, h3);
        *(ushort4*)&Xlo[sidx] = make_ushort4(l0, l1, l2, l3);
    }
    const uint4* WhiG = (const uint4*)(WhiT + woff);
    const uint4* WloG = (const uint4*)(WloT + woff);
    #pragma unroll
    for (int i = 0; i < 8; ++i) {
        int f = t + i * 256;            // 0..2047 16B chunks
        int n = f >> 4, k8 = f & 15;
        int sidx = (n * HD + k8 * 8) ^ ((n & 7) << 3);
        *(uint4*)&Bhi[sidx] = WhiG[f];
        *(uint4*)&Blo[sidx] = WloG[f];
    }
    __syncthreads();

    int lane = t & 63, wv = t >> 6;
    int wr = (wv >> 1) * 64, wc = (wv & 1) * 64;
    int fr = lane & 15, fq = lane >> 4;

    v4f acc[4][4];
    #pragma unroll
    for (int m = 0; m < 4; ++m)
        #pragma unroll
        for (int n = 0; n < 4; ++n)
            acc[m][n] = (v4f){0.f, 0.f, 0.f, 0.f};

    #pragma unroll
    for (int kk = 0; kk < 4; ++kk) {
        int k0 = kk * 32 + fq * 8;
        v8s ahi[4], alo[4], bhi[4], blo[4];
        #pragma unroll
        for (int m = 0; m < 4; ++m) {
            int row = wr + m * 16 + fr;
            int sidx = (row * HD + k0) ^ ((row & 7) << 3);
            ahi[m] = *(const v8s*)&Xhi[sidx];
            alo[m] = *(const v8s*)&Xlo[sidx];
        }
        #pragma unroll
        for (int n = 0; n < 4; ++n) {
            int rowb = wc + n * 16 + fr;
            int sidx = (rowb * HD + k0) ^ ((rowb & 7) << 3);
            bhi[n] = *(const v8s*)&Bhi[sidx];
            blo[n] = *(const v8s*)&Blo[sidx];
        }
        #pragma unroll
        for (int m = 0; m < 4; ++m)
            #pragma unroll
            for (int n = 0; n < 4; ++n) {
                acc[m][n] = __builtin_amdgcn_mfma_f32_16x16x32_bf16(ahi[m], bhi[n], acc[m][n], 0, 0, 0);
                acc[m][n] = __builtin_amdgcn_mfma_f32_16x16x32_bf16(ahi[m], blo[n], acc[m][n], 0, 0, 0);
                acc[m][n] = __builtin_amdgcn_mfma_f32_16x16x32_bf16(alo[m], bhi[n], acc[m][n], 0, 0, 0);
            }
    }

    #pragma unroll
    for (int m = 0; m < 4; ++m)
        #pragma unroll
        for (int n = 0; n < 4; ++n)
            #pragma unroll
            for (int rg = 0; rg < 4; ++rg)
                Cb[(r0 + wr + m * 16 + fq * 4 + rg) * HD + wc + n * 16 + fr] = acc[m][n][rg];
}

// ---------------------------------------------------------------------------
// GCN aggregation, occupancy-optimized: 16-channel blocks, ushort edge lists.
// grid (8 chblocks, 64 graphs, 2 branches), block 512, ~51 KB LDS -> 3 blk/CU.
// Per node (8-lane group, 2 ch/lane): sum dis[s]*xw[s][c] in CSR order, then
// dn*(agg + self) + bias, relu. Identical op order to the verified r8 kernel.
// ---------------------------------------------------------------------------
__global__ __launch_bounds__(512, 6) void agg_graph(const float* __restrict__ xw,
                                                    const int* __restrict__ csr_src,
                                                    const int* __restrict__ offs,
                                                    const float* __restrict__ dis,
                                                    const float* __restrict__ bsA,
                                                    const float* __restrict__ bsB,
                                                    float* __restrict__ out,
                                                    int layer) {
    __shared__ float xs[NPG][16];          // 32 KB, pre-scaled by dis[src]
    __shared__ unsigned short es[EPG];     // 16 KB localized src indices
    __shared__ unsigned short eo[NPG + 1]; // 1 KB local edge offsets
    __shared__ float ds_l[NPG];            // 2 KB dis of graph nodes

    int cb = blockIdx.x, g = blockIdx.y, br = blockIdx.z;
    int t = threadIdx.x;
    const float* xw_b  = xw      + (size_t)br * NN * HD;
    const int*   csr_b = csr_src + (size_t)br * NE;
    const int*   off_b = offs    + (size_t)br * (NN + 1);
    const float* dis_b = dis     + (size_t)br * NN;
    const float* bias  = (br ? bsB : bsA) + (size_t)layer * HD;
    float*       out_b = out     + (size_t)br * NN * HD;
    int nbase = g * NPG;
    int ebase = g * EPG;
    int c0 = cb * 16;

    #pragma unroll
    for (int i = t; i < NPG * 4; i += 512) {        // 4 float4 per row
        int row = i >> 2, f4 = i & 3;
        float dsrc = dis_b[nbase + row];
        float4 v = *(const float4*)&xw_b[(size_t)(nbase + row) * HD + c0 + f4 * 4];
        v.x *= dsrc; v.y *= dsrc; v.z *= dsrc; v.w *= dsrc;
        *(float4*)&xs[row][f4 * 4] = v;
    }
    #pragma unroll
    for (int i = t; i < EPG; i += 512)
        es[i] = (unsigned short)(csr_b[ebase + i] - nbase);
    if (t < NPG) {
        eo[t] = (unsigned short)(off_b[nbase + t] - ebase);
        ds_l[t] = dis_b[nbase + t];
    }
    if (t == 0) eo[NPG] = (unsigned short)EPG;
    __syncthreads();

    int ch2 = (t & 7) * 2;
    float b0 = bias[c0 + ch2], b1 = bias[c0 + ch2 + 1];
    for (int n = t >> 3; n < NPG; n += 64) {
        float dn = ds_l[n];
        int e0 = eo[n], e1 = eo[n + 1];
        float ax = 0.f, ay = 0.f;
        for (int e = e0; e < e1; ++e) {
            int s = es[e];
            float2 xv = *(const float2*)&xs[s][ch2];
            ax += xv.x; ay += xv.y;
        }
        float2 sv = *(const float2*)&xs[n][ch2];
        float vx = dn * (ax + sv.x) + b0;
        float vy = dn * (ay + sv.y) + b1;
        float2 o2 = make_float2(vx > 0.f ? vx : 0.f, vy > 0.f ? vy : 0.f);
        *(float2*)&out_b[(size_t)(nbase + n) * HD + c0 + ch2] = o2;
    }
}

// ---------------------------------------------------------------------------
// Fused sort_pool + conv1d + relu. grid (NB, 2 branches), block 512.
// Bitonic sort 512 (desc by ch127, ties->lower idx = jax top_k), then
// conv over the top-30 rows entirely from LDS.
// ---------------------------------------------------------------------------
__global__ __launch_bounds__(512) void sortconv_k(const float* __restrict__ x,
                                                  const float* __restrict__ cwA,
                                                  const float* __restrict__ cwB,
                                                  const float* __restrict__ cbA,
                                                  const float* __restrict__ cbB,
                                                  float* __restrict__ cbuf) {
    __shared__ float v[512];
    __shared__ int   idx[512];
    __shared__ float xs[KP][CPAD];      // 15.8 KB
    __shared__ float wl[CO][5][HD];     // 80 KB  wl[o][kk][i]
    int g = blockIdx.x, br = blockIdx.y, t = threadIdx.x;
    const float* xb = x + (size_t)br * NN * HD;
    const float* convW = br ? cwB : cwA;
    const float* convb = br ? cbB : cbA;
    float* cb = cbuf + (size_t)br * NB * FEAT;

    v[t] = xb[(size_t)(g * NPG + t) * HD + (HD - 1)];
    idx[t] = t;
    // stage conv weights while sorting (independent of v/idx)
    for (int l = t; l < CO * 5 * HD; l += 512) {
        int o = l / (5 * HD), r = l % (5 * HD), kk = r / HD, i = r % HD;
        wl[o][kk][i] = convW[(o * HD + i) * 5 + kk];
    }
    __syncthreads();
    for (int k = 2; k <= 512; k <<= 1) {
        for (int j = k >> 1; j > 0; j >>= 1) {
            int ixj = t ^ j;
            if (ixj > t) {
                float va = v[t], vb = v[ixj];
                int ia = idx[t], ib = idx[ixj];
                bool aBefore = (va > vb) || (va == vb && ia < ib);
                bool dirDesc = ((t & k) == 0);
                if (dirDesc ? !aBefore : aBefore) {
                    v[t] = vb; v[ixj] = va;
                    idx[t] = ib; idx[ixj] = ia;
                }
            }
            __syncthreads();
        }
    }
    // stage top-30 rows
    for (int l = t; l < KP * (HD / 4); l += 512) {      // 960 float4
        int r = l >> 5, c4 = l & 31;
        float4 vv = *(const float4*)&xb[(size_t)(g * NPG + idx[r]) * HD + c4 * 4];
        *(float4*)&xs[r][c4 * 4] = vv;
    }
    __syncthreads();
    // conv: 832 outputs, threads take j = t, t+512
    for (int j = t; j < CO * CT; j += 512) {
        int o = j / CT, tt = j % CT;
        float acc = convb[o];
        #pragma unroll
        for (int kk = 0; kk < 5; ++kk) {
            const float* xr = &xs[tt + kk][0];
            const float* wr = &wl[o][kk][0];
            #pragma unroll 8
            for (int i4 = 0; i4 < HD / 4; ++i4) {
                float4 a = *(const float4*)&xr[i4 * 4];
                float4 w = *(const float4*)&wr[i4 * 4];
                acc += a.x * w.x + a.y * w.y + a.z * w.z + a.w * w.w;
            }
        }
        cb[g * FEAT + j] = acc > 0.f ? acc : 0.f;
    }
}

// ---------------------------------------------------------------------------
// Head
// ---------------------------------------------------------------------------
__global__ __launch_bounds__(128) void lin1_part(const float* __restrict__ cbuf,
                                                 const float* __restrict__ W,
                                                 float* __restrict__ out1p) {
    __shared__ float fs[128];
    int b = blockIdx.x, kc = blockIdx.y, t = threadIdx.x;
    int r0 = kc * 128;
    int r = r0 + t;
    fs[t] = (r < FEAT) ? cbuf[(size_t)b * FEAT + r]
                       : cbuf[(size_t)NB * FEAT + (size_t)b * FEAT + (r - FEAT)];
    __syncthreads();
    float acc = 0.f;
    #pragma unroll 8
    for (int rr = 0; rr < 128; ++rr)
        acc += fs[rr] * W[(size_t)(r0 + rr) * HD + t];
    out1p[((size_t)b * KCH + kc) * HD + t] = acc;
}

// lin1_red + lin2 + lin3 + final log_softmax + loss add. grid NB, block 128.
__global__ __launch_bounds__(128) void tail_k(const float* __restrict__ out1p,
                                              const float* __restrict__ b1,
                                              const float* __restrict__ W2,
                                              const float* __restrict__ b2,
                                              const float* __restrict__ W3,
                                              const float* __restrict__ b3,
                                              const float* __restrict__ loss,
                                              float* __restrict__ out) {
    __shared__ float o1[HD];
    __shared__ float o2[64];
    __shared__ float x3s[2];
    int b = blockIdx.x, t = threadIdx.x;
    float acc = b1[t];
    #pragma unroll
    for (int kc = 0; kc < KCH; ++kc) acc += out1p[((size_t)b * KCH + kc) * HD + t];
    o1[t] = acc > 0.f ? acc : 0.f;
    __syncthreads();
    if (t < 64) {
        float a2 = b2[t];
        #pragma unroll 8
        for (int r = 0; r < HD; ++r) a2 += o1[r] * W2[r * 64 + t];
        o2[t] = a2 > 0.f ? a2 : 0.f;
    }
    __syncthreads();
    if (t < 2) {
        float a3 = b3[t];
        for (int r = 0; r < 64; ++r) a3 += o2[r] * W3[r * 2 + t];
        x3s[t] = a3;
    }
    __syncthreads();
    if (t == 0) {
        float l0 = x3s[0], l1 = x3s[1];
        float m = fmaxf(l0, l1);
        float lse = m + logf(expf(l0 - m) + expf(l1 - m));
        float L = *loss;
        out[b * 2]     = l0 - lse + L;
        out[b * 2 + 1] = l1 - lse + L;
    }
}

// also zeroes the loss accumulator (runs before clip_k, stream-ordered)
__global__ __launch_bounds__(64) void norm_k(const float* __restrict__ cbuf,
                                             float* __restrict__ inv_norm,
                                             float* __restrict__ loss) {
    int i = blockIdx.x;            // 0..127 (64 sc rows then 64 fc rows)
    int t = threadIdx.x;
    if (i == 0 && t == 0) *loss = 0.f;
    const float* row = cbuf + (size_t)i * FEAT;
    float s = 0.f;
    for (int r = t; r < FEAT; r += 64) s += row[r] * row[r];
    #pragma unroll
    for (int o = 32; o; o >>= 1) s += __shfl_down(s, o);
    if (t == 0) inv_norm[i] = rsqrtf(s);
}

// grid (64, 2): blockIdx.x = i, blockIdx.y = branch. 512 threads:
// 8 K-chunks (104 elems) x 64 j. Partials LDS-reduced, wave 0 finishes.
__global__ __launch_bounds__(512) void clip_k(const float* __restrict__ cbuf,
                                              const float* __restrict__ inv_norm,
                                              float* __restrict__ loss) {
    __shared__ float ai_s[FEAT];
    __shared__ float dpS[8][64];
    __shared__ float dnS[8][64];
    int i = blockIdx.x, br = blockIdx.y;
    int t = threadIdx.x;
    const float* A  = cbuf + (br ? (size_t)NB * FEAT : 0);
    const float* Bm = cbuf + (br ? 0 : (size_t)NB * FEAT);
    const float* invA = inv_norm + (br ? 64 : 0);
    const float* invB = inv_norm + (br ? 0 : 64);
    for (int r = t; r < FEAT; r += 512) ai_s[r] = A[(size_t)i * FEAT + r];
    __syncthreads();
    int j = t & 63, rc = t >> 6;
    float dp = 0.f, dn = 0.f;
    #pragma unroll 8
    for (int r = rc * 104; r < rc * 104 + 104; ++r) {
        float a = ai_s[r];
        dp += a * Bm[(size_t)j * FEAT + r];
        dn += a * A[(size_t)j * FEAT + r];
    }
    dpS[rc][j] = dp; dnS[rc][j] = dn;
    __syncthreads();
    if (t < 64) {
        float dpt = 0.f, dnt = 0.f;
        #pragma unroll
        for (int c = 0; c < 8; ++c) { dpt += dpS[c][t]; dnt += dnS[c][t]; }
        float lp = dpt * invA[i] * invB[t] * 2.0f;                     // /TEMP
        float ln = (t == i) ? 0.0f : 0.8f * dnt * invA[i] * invA[t] * 2.0f;
        float m = fmaxf(lp, ln);
        #pragma unroll
        for (int o = 32; o; o >>= 1) m = fmaxf(m, __shfl_xor(m, o));
        float s = expf(lp - m) + expf(ln - m);
        #pragma unroll
        for (int o = 32; o; o >>= 1) s += __shfl_xor(s, o);
        float lse = m + logf(s);
        float lpi = __shfl(lp, i);
        if (t == 0) atomicAdd(loss, (lse - lpi) * (1.0f / 128.0f));
    }
}

// ---------------------------------------------------------------------------
extern "C" void kernel_launch(void* const* d_in, const int* in_sizes, int n_in,
                              void* d_out, int out_size, void* d_ws, size_t ws_size,
                              hipStream_t stream) {
    (void)in_sizes; (void)n_in; (void)out_size; (void)ws_size;

    char* w = (char*)d_ws;
    auto alloc = [&](size_t bytes) -> char* {
        char* p = w;
        w += (bytes + 255) & ~(size_t)255;
        return p;
    };

    int*   offs    = (int*)  alloc((size_t)2 * (NN + 1) * 4);
    int*   csr_src = (int*)  alloc((size_t)2 * NE * 4);
    float* dis     = (float*)alloc((size_t)2 * NN * 4);
    float* xw      = (float*)alloc((size_t)2 * NN * HD * 4);
    float* buf0    = (float*)alloc((size_t)2 * NN * HD * 4);
    float* buf1    = (float*)alloc((size_t)2 * NN * HD * 4);
    float* cbuf    = (float*)alloc((size_t)2 * NB * FEAT * 4);
    float* inv_nrm = (float*)alloc(128 * 4);
    float* out1p   = (float*)alloc((size_t)NB * KCH * HD * 4);
    float* loss    = (float*)alloc(4);
    unsigned short* whiT = (unsigned short*)alloc((size_t)2 * 4 * HD * HD * 2);
    unsigned short* wloT = (unsigned short*)alloc((size_t)2 * 4 * HD * HD * 2);

    const float* sc_x  = (const float*)d_in[0];
    const float* fc_x  = (const float*)d_in[1];
    const int*   edgeA = (const int*)  d_in[2];
    const int*   edgeB = (const int*)  d_in[3];
    const float* WsA   = (const float*)d_in[4];
    const float* bsA   = (const float*)d_in[5];
    const float* WsB   = (const float*)d_in[6];
    const float* bsB   = (const float*)d_in[7];
    const float* cwA   = (const float*)d_in[8];
    const float* cbA   = (const float*)d_in[9];
    const float* cwB   = (const float*)d_in[10];
    const float* cbB   = (const float*)d_in[11];

    csr_build<<<128, 512, 0, stream>>>(edgeA, edgeB, csr_src, offs, dis);
    wprep_k<<<8, 1024, 0, stream>>>(WsA, WsB, whiT, wloT);

    // 4 GCN layers, both branches per dispatch
    const float* cur0 = sc_x;
    const float* cur1 = fc_x;
    float* bufs[2] = {buf0, buf1};
    for (int l = 0; l < 4; ++l) {
        gemm_mfma<<<dim3(NN / 128, 2), 256, 0, stream>>>(cur0, cur1, whiT, wloT, xw, l);
        float* nxt = bufs[l & 1];
        agg_graph<<<dim3(8, NB, 2), 512, 0, stream>>>(xw, csr_src, offs, dis,
                                                      bsA, bsB, nxt, l);
        cur0 = nxt;
        cur1 = nxt + (size_t)NN * HD;
    }

    // fused sort-pool + conv, both branches
    sortconv_k<<<dim3(NB, 2), 512, 0, stream>>>(cur0, cwA, cwB, cbA, cbB, cbuf);

    // head + CLIP loss (norm_k also zeroes the loss accumulator)
    norm_k<<<128, 64, 0, stream>>>(cbuf, inv_nrm, loss);
    clip_k<<<dim3(64, 2), 512, 0, stream>>>(cbuf, inv_nrm, loss);

    lin1_part<<<dim3(NB, KCH), 128, 0, stream>>>(cbuf, (const float*)d_in[12], out1p);
    tail_k<<<NB, 128, 0, stream>>>(out1p, (const float*)d_in[13],
                                   (const float*)d_in[14], (const float*)d_in[15],
                                   (const float*)d_in[16], (const float*)d_in[17],
                                   loss, (float*)d_out);
}

// Round 12
// 452.628 us; speedup vs baseline: 2.8265x; 1.0182x over previous
//
#include <hip/hip_runtime.h>
#include <hip/hip_bf16.h>
#include <math.h>

#define NB    64      // graphs
#define NPG   512     // nodes per graph
#define NN    (NB*NPG)   // 32768 nodes
#define NE    524288  // edges per branch
#define EPG   (NE/NB)    // 8192 edges per graph
#define HD    128     // hidden dim
#define KP    30      // sort-pool k
#define CT    26      // K-4 conv output length
#define CO    32      // conv out channels
#define FEAT  (CO*CT) // 832 branch feature size
#define CPAD  132     // conv LDS row stride (4 mod 32 banks, 16B-aligned rows)
#define KCH   13      // lin1 K chunks (13*128 = 1664)
#define OPG   (NPG+1) // offsets per graph (local, ushort)

typedef short v8s __attribute__((ext_vector_type(8)));
typedef float v4f __attribute__((ext_vector_type(4)));

__device__ __forceinline__ unsigned short f2bf_rne(float x) {
    union { float f; unsigned u; } a; a.f = x;
    return (unsigned short)((a.u + 0x7fffu + ((a.u >> 16) & 1u)) >> 16);
}
__device__ __forceinline__ float bf2f(unsigned short b) {
    union { float f; unsigned u; } a; a.u = ((unsigned)b) << 16; return a.f;
}

// ---------------------------------------------------------------------------
// Fused CSR build: count (LDS atomics) + scan + dis + fill, both branches.
// grid 128 (g = bid&63, br = bid>>6), block 512.
// Outputs: csr_us (ushort LOCAL src ids), offs_us (ushort local offsets,
// [br][g*OPG + n]), dis (fp32).
// ---------------------------------------------------------------------------
__global__ __launch_bounds__(512) void csr_build(const int* __restrict__ eA,
                                                 const int* __restrict__ eB,
                                                 unsigned short* __restrict__ csr_us,
                                                 unsigned short* __restrict__ offs_us,
                                                 float* __restrict__ dis) {
    __shared__ int cnt[NPG];
    __shared__ int cur[NPG];
    __shared__ int wsum[8];
    int bid = blockIdx.x;
    int br = bid >> 6, g = bid & 63;
    const int* edges = br ? eB : eA;
    unsigned short* csr    = csr_us  + (size_t)br * NE;
    unsigned short* offs_b = offs_us + (size_t)br * NB * OPG;
    float* dis_b  = dis + (size_t)br * NN;
    int t = threadIdx.x;
    int nbase = g * NPG, ebase = g * EPG;
    const int* src = edges + ebase;
    const int* dst = edges + NE + ebase;

    cnt[t] = 0;
    __syncthreads();
    for (int i = t; i < EPG; i += 512) atomicAdd(&cnt[dst[i] - nbase], 1);
    __syncthreads();

    int v = cnt[t];
    int x = v;
    #pragma unroll
    for (int o = 1; o < 64; o <<= 1) {
        int y = __shfl_up(x, o);
        if ((t & 63) >= o) x += y;
    }
    int wid = t >> 6;
    if ((t & 63) == 63) wsum[wid] = x;
    __syncthreads();
    if (t == 0) {
        int run = 0;
        #pragma unroll
        for (int i = 0; i < 8; ++i) { int c = wsum[i]; wsum[i] = run; run += c; }
    }
    __syncthreads();
    int excl = wsum[wid] + x - v;              // local exclusive prefix
    offs_b[g * OPG + t] = (unsigned short)excl;
    cur[t] = excl;
    dis_b[nbase + t] = rsqrtf((float)v + 1.0f);
    if (t == 0) offs_b[g * OPG + NPG] = (unsigned short)EPG;
    __syncthreads();

    for (int i = t; i < EPG; i += 512) {
        int d = dst[i] - nbase;
        int p = atomicAdd(&cur[d], 1);
        csr[ebase + p] = (unsigned short)(src[i] - nbase);
    }
}

// ---------------------------------------------------------------------------
// Weight prep via LDS-tile transpose: coalesced reads AND writes.
// grid 8 (bl = br*4+layer), block 1024.
// ---------------------------------------------------------------------------
__global__ __launch_bounds__(1024) void wprep_k(const float* __restrict__ WA,
                                                const float* __restrict__ WB,
                                                unsigned short* __restrict__ hiT,
                                                unsigned short* __restrict__ loT) {
    __shared__ unsigned short hi[128][130];   // 130-pad: conflict-free transpose
    __shared__ unsigned short lo[128][130];
    int bl = blockIdx.x;
    const float* W = (bl >= 4 ? WB : WA) + ((size_t)(bl & 3) << 14);
    int t = threadIdx.x;
    for (int i = t; i < 16384; i += 1024) {       // read W[k][n] coalesced
        int k = i >> 7, n = i & 127;
        float x = W[i];
        unsigned short h = f2bf_rne(x);
        hi[n][k] = h;
        lo[n][k] = f2bf_rne(x - bf2f(h));
    }
    __syncthreads();
    size_t base = (size_t)bl << 14;
    for (int i = t; i < 16384; i += 1024) {       // write hiT[n][k] coalesced
        int n = i >> 7, k = i & 127;
        hiT[base + i] = hi[n][k];
        loT[base + i] = lo[n][k];
    }
}

// ---------------------------------------------------------------------------
// MFMA GEMM, both branches: grid (NN/128, 2), block 256 (4 waves).
// C[br][M][128] = X_br[M][128] @ W[br][l][128][128], fp32 via split-bf16.
// ---------------------------------------------------------------------------
__global__ __launch_bounds__(256) void gemm_mfma(const float* __restrict__ X0,
                                                 const float* __restrict__ X1,
                                                 const unsigned short* __restrict__ WhiT,
                                                 const unsigned short* __restrict__ WloT,
                                                 float* __restrict__ C,
                                                 int layer) {
    __shared__ __align__(16) unsigned short Xhi[128 * HD];
    __shared__ __align__(16) unsigned short Xlo[128 * HD];
    __shared__ __align__(16) unsigned short Bhi[128 * HD];
    __shared__ __align__(16) unsigned short Blo[128 * HD];

    int t = threadIdx.x;
    int br = blockIdx.y;
    size_t r0 = (size_t)blockIdx.x * 128;
    const float* X = br ? X1 : X0;
    size_t woff = (size_t)(br * 4 + layer) << 14;
    float* Cb = C + (size_t)br * NN * HD;

    const float4* Xg = (const float4*)(X + r0 * HD);
    #pragma unroll
    for (int i = 0; i < 16; ++i) {
        int f = t + i * 256;            // 0..4095 float4 slots
        int row = f >> 5, c4 = f & 31;
        float4 v = Xg[f];
        unsigned short h0 = f2bf_rne(v.x), h1 = f2bf_rne(v.y),
                       h2 = f2bf_rne(v.z), h3 = f2bf_rne(v.w);
        unsigned short l0 = f2bf_rne(v.x - bf2f(h0)), l1 = f2bf_rne(v.y - bf2f(h1)),
                       l2 = f2bf_rne(v.z - bf2f(h2)), l3 = f2bf_rne(v.w - bf2f(h3));
        int sidx = (row * HD + c4 * 4) ^ ((row & 7) << 3);
        *(ushort4*)&Xhi[sidx] = make_ushort4(h0, h1, h2, h3);
        *(ushort4*)&Xlo[sidx] = make_ushort4(l0, l1, l2, l3);
    }
    const uint4* WhiG = (const uint4*)(WhiT + woff);
    const uint4* WloG = (const uint4*)(WloT + woff);
    #pragma unroll
    for (int i = 0; i < 8; ++i) {
        int f = t + i * 256;            // 0..2047 16B chunks
        int n = f >> 4, k8 = f & 15;
        int sidx = (n * HD + k8 * 8) ^ ((n & 7) << 3);
        *(uint4*)&Bhi[sidx] = WhiG[f];
        *(uint4*)&Blo[sidx] = WloG[f];
    }
    __syncthreads();

    int lane = t & 63, wv = t >> 6;
    int wr = (wv >> 1) * 64, wc = (wv & 1) * 64;
    int fr = lane & 15, fq = lane >> 4;

    v4f acc[4][4];
    #pragma unroll
    for (int m = 0; m < 4; ++m)
        #pragma unroll
        for (int n = 0; n < 4; ++n)
            acc[m][n] = (v4f){0.f, 0.f, 0.f, 0.f};

    #pragma unroll
    for (int kk = 0; kk < 4; ++kk) {
        int k0 = kk * 32 + fq * 8;
        v8s ahi[4], alo[4], bhi[4], blo[4];
        #pragma unroll
        for (int m = 0; m < 4; ++m) {
            int row = wr + m * 16 + fr;
            int sidx = (row * HD + k0) ^ ((row & 7) << 3);
            ahi[m] = *(const v8s*)&Xhi[sidx];
            alo[m] = *(const v8s*)&Xlo[sidx];
        }
        #pragma unroll
        for (int n = 0; n < 4; ++n) {
            int rowb = wc + n * 16 + fr;
            int sidx = (rowb * HD + k0) ^ ((rowb & 7) << 3);
            bhi[n] = *(const v8s*)&Bhi[sidx];
            blo[n] = *(const v8s*)&Blo[sidx];
        }
        #pragma unroll
        for (int m = 0; m < 4; ++m)
            #pragma unroll
            for (int n = 0; n < 4; ++n) {
                acc[m][n] = __builtin_amdgcn_mfma_f32_16x16x32_bf16(ahi[m], bhi[n], acc[m][n], 0, 0, 0);
                acc[m][n] = __builtin_amdgcn_mfma_f32_16x16x32_bf16(ahi[m], blo[n], acc[m][n], 0, 0, 0);
                acc[m][n] = __builtin_amdgcn_mfma_f32_16x16x32_bf16(alo[m], bhi[n], acc[m][n], 0, 0, 0);
            }
    }

    #pragma unroll
    for (int m = 0; m < 4; ++m)
        #pragma unroll
        for (int n = 0; n < 4; ++n)
            #pragma unroll
            for (int rg = 0; rg < 4; ++rg)
                Cb[(r0 + wr + m * 16 + fq * 4 + rg) * HD + wc + n * 16 + fr] = acc[m][n][rg];
}

// ---------------------------------------------------------------------------
// GCN aggregation: 16-ch blocks, ushort CSR, 4x-unrolled gather for ILP.
// grid (8 chblocks, 64 graphs, 2 branches), block 512, ~51 KB LDS -> 3 blk/CU.
// Add order per node preserved exactly (sequential adds in CSR order).
// ---------------------------------------------------------------------------
__global__ __launch_bounds__(512, 6) void agg_graph(const float* __restrict__ xw,
                                                    const unsigned short* __restrict__ csr_us,
                                                    const unsigned short* __restrict__ offs_us,
                                                    const float* __restrict__ dis,
                                                    const float* __restrict__ bsA,
                                                    const float* __restrict__ bsB,
                                                    float* __restrict__ out,
                                                    int layer) {
    __shared__ float xs[NPG][16];                       // 32 KB, dis[src]-scaled
    __shared__ __align__(16) unsigned short es[EPG];    // 16 KB local src ids
    __shared__ unsigned short eo[NPG + 1];              // 1 KB local offsets
    __shared__ float ds_l[NPG];                         // 2 KB

    int cb = blockIdx.x, g = blockIdx.y, br = blockIdx.z;
    int t = threadIdx.x;
    const float* xw_b  = xw  + (size_t)br * NN * HD;
    const float* dis_b = dis + (size_t)br * NN;
    const float* bias  = (br ? bsB : bsA) + (size_t)layer * HD;
    float*       out_b = out + (size_t)br * NN * HD;
    int nbase = g * NPG;
    int c0 = cb * 16;

    #pragma unroll
    for (int i = t; i < NPG * 4; i += 512) {        // 4 float4 per row
        int row = i >> 2, f4 = i & 3;
        float dsrc = dis_b[nbase + row];
        float4 v = *(const float4*)&xw_b[(size_t)(nbase + row) * HD + c0 + f4 * 4];
        v.x *= dsrc; v.y *= dsrc; v.z *= dsrc; v.w *= dsrc;
        *(float4*)&xs[row][f4 * 4] = v;
    }
    // es: copy 8192 ushorts as 4096 uints (coalesced, no conversion)
    {
        const uint* cs = (const uint*)(csr_us + (size_t)br * NE + (size_t)g * EPG);
        uint* esd = (uint*)es;
        #pragma unroll
        for (int i = t; i < EPG / 2; i += 512) esd[i] = cs[i];
    }
    {
        const unsigned short* ob = offs_us + (size_t)br * NB * OPG + (size_t)g * OPG;
        if (t < NPG) eo[t] = ob[t];
        if (t == 0) eo[NPG] = (unsigned short)EPG;
        if (t < NPG) ds_l[t] = dis_b[nbase + t];
    }
    __syncthreads();

    int ch2 = (t & 7) * 2;
    float b0 = bias[c0 + ch2], b1 = bias[c0 + ch2 + 1];
    for (int n = t >> 3; n < NPG; n += 64) {
        float dn = ds_l[n];
        int e0 = eo[n], e1 = eo[n + 1];
        float ax = 0.f, ay = 0.f;
        int e = e0;
        for (; e + 4 <= e1; e += 4) {               // 4 independent gathers
            int s0 = es[e], s1 = es[e + 1], s2 = es[e + 2], s3 = es[e + 3];
            float2 v0 = *(const float2*)&xs[s0][ch2];
            float2 v1 = *(const float2*)&xs[s1][ch2];
            float2 v2 = *(const float2*)&xs[s2][ch2];
            float2 v3 = *(const float2*)&xs[s3][ch2];
            ax += v0.x; ay += v0.y;                 // adds stay in CSR order
            ax += v1.x; ay += v1.y;
            ax += v2.x; ay += v2.y;
            ax += v3.x; ay += v3.y;
        }
        for (; e < e1; ++e) {
            int s = es[e];
            float2 xv = *(const float2*)&xs[s][ch2];
            ax += xv.x; ay += xv.y;
        }
        float2 sv = *(const float2*)&xs[n][ch2];
        float vx = dn * (ax + sv.x) + b0;
        float vy = dn * (ay + sv.y) + b1;
        float2 o2 = make_float2(vx > 0.f ? vx : 0.f, vy > 0.f ? vy : 0.f);
        *(float2*)&out_b[(size_t)(nbase + n) * HD + c0 + ch2] = o2;
    }
}

// ---------------------------------------------------------------------------
// Fused sort_pool + conv1d + relu. grid (NB, 2 branches), block 512.
// ---------------------------------------------------------------------------
__global__ __launch_bounds__(512) void sortconv_k(const float* __restrict__ x,
                                                  const float* __restrict__ cwA,
                                                  const float* __restrict__ cwB,
                                                  const float* __restrict__ cbA,
                                                  const float* __restrict__ cbB,
                                                  float* __restrict__ cbuf) {
    __shared__ float v[512];
    __shared__ int   idx[512];
    __shared__ float xs[KP][CPAD];      // 15.8 KB
    __shared__ float wl[CO][5][HD];     // 80 KB  wl[o][kk][i]
    int g = blockIdx.x, br = blockIdx.y, t = threadIdx.x;
    const float* xb = x + (size_t)br * NN * HD;
    const float* convW = br ? cwB : cwA;
    const float* convb = br ? cbB : cbA;
    float* cb = cbuf + (size_t)br * NB * FEAT;

    v[t] = xb[(size_t)(g * NPG + t) * HD + (HD - 1)];
    idx[t] = t;
    for (int l = t; l < CO * 5 * HD; l += 512) {
        int o = l / (5 * HD), r = l % (5 * HD), kk = r / HD, i = r % HD;
        wl[o][kk][i] = convW[(o * HD + i) * 5 + kk];
    }
    __syncthreads();
    for (int k = 2; k <= 512; k <<= 1) {
        for (int j = k >> 1; j > 0; j >>= 1) {
            int ixj = t ^ j;
            if (ixj > t) {
                float va = v[t], vb = v[ixj];
                int ia = idx[t], ib = idx[ixj];
                bool aBefore = (va > vb) || (va == vb && ia < ib);
                bool dirDesc = ((t & k) == 0);
                if (dirDesc ? !aBefore : aBefore) {
                    v[t] = vb; v[ixj] = va;
                    idx[t] = ib; idx[ixj] = ia;
                }
            }
            __syncthreads();
        }
    }
    for (int l = t; l < KP * (HD / 4); l += 512) {      // 960 float4
        int r = l >> 5, c4 = l & 31;
        float4 vv = *(const float4*)&xb[(size_t)(g * NPG + idx[r]) * HD + c4 * 4];
        *(float4*)&xs[r][c4 * 4] = vv;
    }
    __syncthreads();
    for (int j = t; j < CO * CT; j += 512) {
        int o = j / CT, tt = j % CT;
        float acc = convb[o];
        #pragma unroll
        for (int kk = 0; kk < 5; ++kk) {
            const float* xr = &xs[tt + kk][0];
            const float* wr = &wl[o][kk][0];
            #pragma unroll 8
            for (int i4 = 0; i4 < HD / 4; ++i4) {
                float4 a = *(const float4*)&xr[i4 * 4];
                float4 w = *(const float4*)&wr[i4 * 4];
                acc += a.x * w.x + a.y * w.y + a.z * w.z + a.w * w.w;
            }
        }
        cb[g * FEAT + j] = acc > 0.f ? acc : 0.f;
    }
}

// ---------------------------------------------------------------------------
// Head
// ---------------------------------------------------------------------------
__global__ __launch_bounds__(128) void lin1_part(const float* __restrict__ cbuf,
                                                 const float* __restrict__ W,
                                                 float* __restrict__ out1p) {
    __shared__ float fs[128];
    int b = blockIdx.x, kc = blockIdx.y, t = threadIdx.x;
    int r0 = kc * 128;
    int r = r0 + t;
    fs[t] = (r < FEAT) ? cbuf[(size_t)b * FEAT + r]
                       : cbuf[(size_t)NB * FEAT + (size_t)b * FEAT + (r - FEAT)];
    __syncthreads();
    float acc = 0.f;
    #pragma unroll 8
    for (int rr = 0; rr < 128; ++rr)
        acc += fs[rr] * W[(size_t)(r0 + rr) * HD + t];
    out1p[((size_t)b * KCH + kc) * HD + t] = acc;
}

// lin1_red + lin2 + lin3 + final log_softmax + loss add. grid NB, block 128.
__global__ __launch_bounds__(128) void tail_k(const float* __restrict__ out1p,
                                              const float* __restrict__ b1,
                                              const float* __restrict__ W2,
                                              const float* __restrict__ b2,
                                              const float* __restrict__ W3,
                                              const float* __restrict__ b3,
                                              const float* __restrict__ loss,
                                              float* __restrict__ out) {
    __shared__ float o1[HD];
    __shared__ float o2[64];
    __shared__ float x3s[2];
    int b = blockIdx.x, t = threadIdx.x;
    float acc = b1[t];
    #pragma unroll
    for (int kc = 0; kc < KCH; ++kc) acc += out1p[((size_t)b * KCH + kc) * HD + t];
    o1[t] = acc > 0.f ? acc : 0.f;
    __syncthreads();
    if (t < 64) {
        float a2 = b2[t];
        #pragma unroll 8
        for (int r = 0; r < HD; ++r) a2 += o1[r] * W2[r * 64 + t];
        o2[t] = a2 > 0.f ? a2 : 0.f;
    }
    __syncthreads();
    if (t < 2) {
        float a3 = b3[t];
        for (int r = 0; r < 64; ++r) a3 += o2[r] * W3[r * 2 + t];
        x3s[t] = a3;
    }
    __syncthreads();
    if (t == 0) {
        float l0 = x3s[0], l1 = x3s[1];
        float m = fmaxf(l0, l1);
        float lse = m + logf(expf(l0 - m) + expf(l1 - m));
        float L = *loss;
        out[b * 2]     = l0 - lse + L;
        out[b * 2 + 1] = l1 - lse + L;
    }
}

// also zeroes the loss accumulator (runs before clip_k, stream-ordered)
__global__ __launch_bounds__(64) void norm_k(const float* __restrict__ cbuf,
                                             float* __restrict__ inv_norm,
                                             float* __restrict__ loss) {
    int i = blockIdx.x;            // 0..127 (64 sc rows then 64 fc rows)
    int t = threadIdx.x;
    if (i == 0 && t == 0) *loss = 0.f;
    const float* row = cbuf + (size_t)i * FEAT;
    float s = 0.f;
    for (int r = t; r < FEAT; r += 64) s += row[r] * row[r];
    #pragma unroll
    for (int o = 32; o; o >>= 1) s += __shfl_down(s, o);
    if (t == 0) inv_norm[i] = rsqrtf(s);
}

// grid (64, 2): blockIdx.x = i, blockIdx.y = branch. 512 threads.
__global__ __launch_bounds__(512) void clip_k(const float* __restrict__ cbuf,
                                              const float* __restrict__ inv_norm,
                                              float* __restrict__ loss) {
    __shared__ float ai_s[FEAT];
    __shared__ float dpS[8][64];
    __shared__ float dnS[8][64];
    int i = blockIdx.x, br = blockIdx.y;
    int t = threadIdx.x;
    const float* A  = cbuf + (br ? (size_t)NB * FEAT : 0);
    const float* Bm = cbuf + (br ? 0 : (size_t)NB * FEAT);
    const float* invA = inv_norm + (br ? 64 : 0);
    const float* invB = inv_norm + (br ? 0 : 64);
    for (int r = t; r < FEAT; r += 512) ai_s[r] = A[(size_t)i * FEAT + r];
    __syncthreads();
    int j = t & 63, rc = t >> 6;
    float dp = 0.f, dn = 0.f;
    #pragma unroll 8
    for (int r = rc * 104; r < rc * 104 + 104; ++r) {
        float a = ai_s[r];
        dp += a * Bm[(size_t)j * FEAT + r];
        dn += a * A[(size_t)j * FEAT + r];
    }
    dpS[rc][j] = dp; dnS[rc][j] = dn;
    __syncthreads();
    if (t < 64) {
        float dpt = 0.f, dnt = 0.f;
        #pragma unroll
        for (int c = 0; c < 8; ++c) { dpt += dpS[c][t]; dnt += dnS[c][t]; }
        float lp = dpt * invA[i] * invB[t] * 2.0f;                     // /TEMP
        float ln = (t == i) ? 0.0f : 0.8f * dnt * invA[i] * invA[t] * 2.0f;
        float m = fmaxf(lp, ln);
        #pragma unroll
        for (int o = 32; o; o >>= 1) m = fmaxf(m, __shfl_xor(m, o));
        float s = expf(lp - m) + expf(ln - m);
        #pragma unroll
        for (int o = 32; o; o >>= 1) s += __shfl_xor(s, o);
        float lse = m + logf(s);
        float lpi = __shfl(lp, i);
        if (t == 0) atomicAdd(loss, (lse - lpi) * (1.0f / 128.0f));
    }
}

// ---------------------------------------------------------------------------
extern "C" void kernel_launch(void* const* d_in, const int* in_sizes, int n_in,
                              void* d_out, int out_size, void* d_ws, size_t ws_size,
                              hipStream_t stream) {
    (void)in_sizes; (void)n_in; (void)out_size; (void)ws_size;

    char* w = (char*)d_ws;
    auto alloc = [&](size_t bytes) -> char* {
        char* p = w;
        w += (bytes + 255) & ~(size_t)255;
        return p;
    };

    unsigned short* csr_us  = (unsigned short*)alloc((size_t)2 * NE * 2);
    unsigned short* offs_us = (unsigned short*)alloc((size_t)2 * NB * OPG * 2);
    float* dis     = (float*)alloc((size_t)2 * NN * 4);
    float* xw      = (float*)alloc((size_t)2 * NN * HD * 4);
    float* buf0    = (float*)alloc((size_t)2 * NN * HD * 4);
    float* buf1    = (float*)alloc((size_t)2 * NN * HD * 4);
    float* cbuf    = (float*)alloc((size_t)2 * NB * FEAT * 4);
    float* inv_nrm = (float*)alloc(128 * 4);
    float* out1p   = (float*)alloc((size_t)NB * KCH * HD * 4);
    float* loss    = (float*)alloc(4);
    unsigned short* whiT = (unsigned short*)alloc((size_t)2 * 4 * HD * HD * 2);
    unsigned short* wloT = (unsigned short*)alloc((size_t)2 * 4 * HD * HD * 2);

    const float* sc_x  = (const float*)d_in[0];
    const float* fc_x  = (const float*)d_in[1];
    const int*   edgeA = (const int*)  d_in[2];
    const int*   edgeB = (const int*)  d_in[3];
    const float* WsA   = (const float*)d_in[4];
    const float* bsA   = (const float*)d_in[5];
    const float* WsB   = (const float*)d_in[6];
    const float* bsB   = (const float*)d_in[7];
    const float* cwA   = (const float*)d_in[8];
    const float* cbA   = (const float*)d_in[9];
    const float* cwB   = (const float*)d_in[10];
    const float* cbB   = (const float*)d_in[11];

    csr_build<<<128, 512, 0, stream>>>(edgeA, edgeB, csr_us, offs_us, dis);
    wprep_k<<<8, 1024, 0, stream>>>(WsA, WsB, whiT, wloT);

    // 4 GCN layers, both branches per dispatch
    const float* cur0 = sc_x;
    const float* cur1 = fc_x;
    float* bufs[2] = {buf0, buf1};
    for (int l = 0; l < 4; ++l) {
        gemm_mfma<<<dim3(NN / 128, 2), 256, 0, stream>>>(cur0, cur1, whiT, wloT, xw, l);
        float* nxt = bufs[l & 1];
        agg_graph<<<dim3(8, NB, 2), 512, 0, stream>>>(xw, csr_us, offs_us, dis,
                                                      bsA, bsB, nxt, l);
        cur0 = nxt;
        cur1 = nxt + (size_t)NN * HD;
    }

    // fused sort-pool + conv, both branches
    sortconv_k<<<dim3(NB, 2), 512, 0, stream>>>(cur0, cwA, cwB, cbA, cbB, cbuf);

    // head + CLIP loss (norm_k also zeroes the loss accumulator)
    norm_k<<<128, 64, 0, stream>>>(cbuf, inv_nrm, loss);
    clip_k<<<dim3(64, 2), 512, 0, stream>>>(cbuf, inv_nrm, loss);

    lin1_part<<<dim3(NB, KCH), 128, 0, stream>>>(cbuf, (const float*)d_in[12], out1p);
    tail_k<<<NB, 128, 0, stream>>>(out1p, (const float*)d_in[13],
                                   (const float*)d_in[14], (const float*)d_in[15],
                                   (const float*)d_in[16], (const float*)d_in[17],
                                   loss, (float*)d_out);
}

// Round 13
// 417.372 us; speedup vs baseline: 3.0653x; 1.0845x over previous
//
#include <hip/hip_runtime.h>
#include <hip/hip_bf16.h>
#include <math.h>

#define NB    64      // graphs
#define NPG   512     // nodes per graph
#define NN    (NB*NPG)   // 32768 nodes
#define NE    524288  // edges per branch
#define EPG   (NE/NB)    // 8192 edges per graph
#define HD    128     // hidden dim
#define KP    30      // sort-pool k
#define CT    26      // K-4 conv output length
#define CO    32      // conv out channels
#define FEAT  (CO*CT) // 832 branch feature size
#define CPAD  132     // conv LDS row stride (4 mod 32 banks, 16B-aligned rows)
#define KCH   13      // lin1 K chunks (13*128 = 1664)
#define OPG   (NPG+1) // offsets per graph (local, ushort)

typedef short v8s __attribute__((ext_vector_type(8)));
typedef float v4f __attribute__((ext_vector_type(4)));

__device__ __forceinline__ unsigned short f2bf_rne(float x) {
    union { float f; unsigned u; } a; a.f = x;
    return (unsigned short)((a.u + 0x7fffu + ((a.u >> 16) & 1u)) >> 16);
}
__device__ __forceinline__ float bf2f(unsigned short b) {
    union { float f; unsigned u; } a; a.u = ((unsigned)b) << 16; return a.f;
}

// ---------------------------------------------------------------------------
// Fused CSR build: count (LDS atomics) + scan + dis + fill, both branches.
// grid 128 (g = bid&63, br = bid>>6), block 512.
// ---------------------------------------------------------------------------
__global__ __launch_bounds__(512) void csr_build(const int* __restrict__ eA,
                                                 const int* __restrict__ eB,
                                                 unsigned short* __restrict__ csr_us,
                                                 unsigned short* __restrict__ offs_us,
                                                 float* __restrict__ dis) {
    __shared__ int cnt[NPG];
    __shared__ int cur[NPG];
    __shared__ int wsum[8];
    int bid = blockIdx.x;
    int br = bid >> 6, g = bid & 63;
    const int* edges = br ? eB : eA;
    unsigned short* csr    = csr_us  + (size_t)br * NE;
    unsigned short* offs_b = offs_us + (size_t)br * NB * OPG;
    float* dis_b  = dis + (size_t)br * NN;
    int t = threadIdx.x;
    int nbase = g * NPG, ebase = g * EPG;
    const int* src = edges + ebase;
    const int* dst = edges + NE + ebase;

    cnt[t] = 0;
    __syncthreads();
    for (int i = t; i < EPG; i += 512) atomicAdd(&cnt[dst[i] - nbase], 1);
    __syncthreads();

    int v = cnt[t];
    int x = v;
    #pragma unroll
    for (int o = 1; o < 64; o <<= 1) {
        int y = __shfl_up(x, o);
        if ((t & 63) >= o) x += y;
    }
    int wid = t >> 6;
    if ((t & 63) == 63) wsum[wid] = x;
    __syncthreads();
    if (t == 0) {
        int run = 0;
        #pragma unroll
        for (int i = 0; i < 8; ++i) { int c = wsum[i]; wsum[i] = run; run += c; }
    }
    __syncthreads();
    int excl = wsum[wid] + x - v;              // local exclusive prefix
    offs_b[g * OPG + t] = (unsigned short)excl;
    cur[t] = excl;
    dis_b[nbase + t] = rsqrtf((float)v + 1.0f);
    if (t == 0) offs_b[g * OPG + NPG] = (unsigned short)EPG;
    __syncthreads();

    for (int i = t; i < EPG; i += 512) {
        int d = dst[i] - nbase;
        int p = atomicAdd(&cur[d], 1);
        csr[ebase + p] = (unsigned short)(src[i] - nbase);
    }
}

// ---------------------------------------------------------------------------
// Weight prep via LDS-tile transpose: coalesced reads AND writes.
// grid 8 (bl = br*4+layer), block 1024.
// ---------------------------------------------------------------------------
__global__ __launch_bounds__(1024) void wprep_k(const float* __restrict__ WA,
                                                const float* __restrict__ WB,
                                                unsigned short* __restrict__ hiT,
                                                unsigned short* __restrict__ loT) {
    __shared__ unsigned short hi[128][130];   // 130-pad: conflict-free transpose
    __shared__ unsigned short lo[128][130];
    int bl = blockIdx.x;
    const float* W = (bl >= 4 ? WB : WA) + ((size_t)(bl & 3) << 14);
    int t = threadIdx.x;
    for (int i = t; i < 16384; i += 1024) {       // read W[k][n] coalesced
        int k = i >> 7, n = i & 127;
        float x = W[i];
        unsigned short h = f2bf_rne(x);
        hi[n][k] = h;
        lo[n][k] = f2bf_rne(x - bf2f(h));
    }
    __syncthreads();
    size_t base = (size_t)bl << 14;
    for (int i = t; i < 16384; i += 1024) {       // write hiT[n][k] coalesced
        int n = i >> 7, k = i & 127;
        hiT[base + i] = hi[n][k];
        loT[base + i] = lo[n][k];
    }
}

// ---------------------------------------------------------------------------
// MFMA GEMM, both branches: grid (NN/128, 2), block 256 (4 waves).
// C[br][M][128] = X_br[M][128] @ W[br][l][128][128], fp32 via split-bf16.
// ---------------------------------------------------------------------------
__global__ __launch_bounds__(256) void gemm_mfma(const float* __restrict__ X0,
                                                 const float* __restrict__ X1,
                                                 const unsigned short* __restrict__ WhiT,
                                                 const unsigned short* __restrict__ WloT,
                                                 float* __restrict__ C,
                                                 int layer) {
    __shared__ __align__(16) unsigned short Xhi[128 * HD];
    __shared__ __align__(16) unsigned short Xlo[128 * HD];
    __shared__ __align__(16) unsigned short Bhi[128 * HD];
    __shared__ __align__(16) unsigned short Blo[128 * HD];

    int t = threadIdx.x;
    int br = blockIdx.y;
    size_t r0 = (size_t)blockIdx.x * 128;
    const float* X = br ? X1 : X0;
    size_t woff = (size_t)(br * 4 + layer) << 14;
    float* Cb = C + (size_t)br * NN * HD;

    const float4* Xg = (const float4*)(X + r0 * HD);
    #pragma unroll
    for (int i = 0; i < 16; ++i) {
        int f = t + i * 256;            // 0..4095 float4 slots
        int row = f >> 5, c4 = f & 31;
        float4 v = Xg[f];
        unsigned short h0 = f2bf_rne(v.x), h1 = f2bf_rne(v.y),
                       h2 = f2bf_rne(v.z), h3 = f2bf_rne(v.w);
        unsigned short l0 = f2bf_rne(v.x - bf2f(h0)), l1 = f2bf_rne(v.y - bf2f(h1)),
                       l2 = f2bf_rne(v.z - bf2f(h2)), l3 = f2bf_rne(v.w - bf2f(h3));
        int sidx = (row * HD + c4 * 4) ^ ((row & 7) << 3);
        *(ushort4*)&Xhi[sidx] = make_ushort4(h0, h1, h2, h3);
        *(ushort4*)&Xlo[sidx] = make_ushort4(l0, l1, l2, l3);
    }
    const uint4* WhiG = (const uint4*)(WhiT + woff);
    const uint4* WloG = (const uint4*)(WloT + woff);
    #pragma unroll
    for (int i = 0; i < 8; ++i) {
        int f = t + i * 256;            // 0..2047 16B chunks
        int n = f >> 4, k8 = f & 15;
        int sidx = (n * HD + k8 * 8) ^ ((n & 7) << 3);
        *(uint4*)&Bhi[sidx] = WhiG[f];
        *(uint4*)&Blo[sidx] = WloG[f];
    }
    __syncthreads();

    int lane = t & 63, wv = t >> 6;
    int wr = (wv >> 1) * 64, wc = (wv & 1) * 64;
    int fr = lane & 15, fq = lane >> 4;

    v4f acc[4][4];
    #pragma unroll
    for (int m = 0; m < 4; ++m)
        #pragma unroll
        for (int n = 0; n < 4; ++n)
            acc[m][n] = (v4f){0.f, 0.f, 0.f, 0.f};

    #pragma unroll
    for (int kk = 0; kk < 4; ++kk) {
        int k0 = kk * 32 + fq * 8;
        v8s ahi[4], alo[4], bhi[4], blo[4];
        #pragma unroll
        for (int m = 0; m < 4; ++m) {
            int row = wr + m * 16 + fr;
            int sidx = (row * HD + k0) ^ ((row & 7) << 3);
            ahi[m] = *(const v8s*)&Xhi[sidx];
            alo[m] = *(const v8s*)&Xlo[sidx];
        }
        #pragma unroll
        for (int n = 0; n < 4; ++n) {
            int rowb = wc + n * 16 + fr;
            int sidx = (rowb * HD + k0) ^ ((rowb & 7) << 3);
            bhi[n] = *(const v8s*)&Bhi[sidx];
            blo[n] = *(const v8s*)&Blo[sidx];
        }
        #pragma unroll
        for (int m = 0; m < 4; ++m)
            #pragma unroll
            for (int n = 0; n < 4; ++n) {
                acc[m][n] = __builtin_amdgcn_mfma_f32_16x16x32_bf16(ahi[m], bhi[n], acc[m][n], 0, 0, 0);
                acc[m][n] = __builtin_amdgcn_mfma_f32_16x16x32_bf16(ahi[m], blo[n], acc[m][n], 0, 0, 0);
                acc[m][n] = __builtin_amdgcn_mfma_f32_16x16x32_bf16(alo[m], bhi[n], acc[m][n], 0, 0, 0);
            }
    }

    #pragma unroll
    for (int m = 0; m < 4; ++m)
        #pragma unroll
        for (int n = 0; n < 4; ++n)
            #pragma unroll
            for (int rg = 0; rg < 4; ++rg)
                Cb[(r0 + wr + m * 16 + fq * 4 + rg) * HD + wc + n * 16 + fr] = acc[m][n][rg];
}

// ---------------------------------------------------------------------------
// GCN aggregation: 1 node per THREAD, 16 channels in registers.
// grid (8 chblocks, 64 graphs, 2 branches), block 512, ~51 KB LDS -> 3 blk/CU.
// Wave-serial chain = max degree over 64 nodes (~26 steps) instead of
// 8 nodes x 16 edges (~176 steps); 4 independent b128 gathers per step.
// Per-channel add order = CSR order (identical numerics to r12).
// ---------------------------------------------------------------------------
__global__ __launch_bounds__(512, 6) void agg_graph(const float* __restrict__ xw,
                                                    const unsigned short* __restrict__ csr_us,
                                                    const unsigned short* __restrict__ offs_us,
                                                    const float* __restrict__ dis,
                                                    const float* __restrict__ bsA,
                                                    const float* __restrict__ bsB,
                                                    float* __restrict__ out,
                                                    int layer) {
    __shared__ float xs[NPG][16];                       // 32 KB, dis[src]-scaled
    __shared__ __align__(16) unsigned short es[EPG];    // 16 KB local src ids
    __shared__ unsigned short eo[NPG + 1];              // 1 KB local offsets
    __shared__ float ds_l[NPG];                         // 2 KB

    int cb = blockIdx.x, g = blockIdx.y, br = blockIdx.z;
    int t = threadIdx.x;
    const float* xw_b  = xw  + (size_t)br * NN * HD;
    const float* dis_b = dis + (size_t)br * NN;
    const float* bias  = (br ? bsB : bsA) + (size_t)layer * HD;
    float*       out_b = out + (size_t)br * NN * HD;
    int nbase = g * NPG;
    int c0 = cb * 16;

    #pragma unroll
    for (int i = t; i < NPG * 4; i += 512) {        // 4 float4 per row
        int row = i >> 2, f4 = i & 3;
        float dsrc = dis_b[nbase + row];
        float4 v = *(const float4*)&xw_b[(size_t)(nbase + row) * HD + c0 + f4 * 4];
        v.x *= dsrc; v.y *= dsrc; v.z *= dsrc; v.w *= dsrc;
        *(float4*)&xs[row][f4 * 4] = v;
    }
    {
        const uint* cs = (const uint*)(csr_us + (size_t)br * NE + (size_t)g * EPG);
        uint* esd = (uint*)es;
        #pragma unroll
        for (int i = t; i < EPG / 2; i += 512) esd[i] = cs[i];
    }
    {
        const unsigned short* ob = offs_us + (size_t)br * NB * OPG + (size_t)g * OPG;
        eo[t] = ob[t];
        if (t == 0) eo[NPG] = (unsigned short)EPG;
        ds_l[t] = dis_b[nbase + t];
    }
    __syncthreads();

    // one node per thread: t = local node id
    float acc[16];
    #pragma unroll
    for (int c = 0; c < 16; ++c) acc[c] = 0.f;
    int e0 = eo[t], e1 = eo[t + 1];
    for (int e = e0; e < e1; ++e) {
        int s = es[e];
        float4 v0 = *(const float4*)&xs[s][0];
        float4 v1 = *(const float4*)&xs[s][4];
        float4 v2 = *(const float4*)&xs[s][8];
        float4 v3 = *(const float4*)&xs[s][12];
        acc[0]  += v0.x; acc[1]  += v0.y; acc[2]  += v0.z; acc[3]  += v0.w;
        acc[4]  += v1.x; acc[5]  += v1.y; acc[6]  += v1.z; acc[7]  += v1.w;
        acc[8]  += v2.x; acc[9]  += v2.y; acc[10] += v2.z; acc[11] += v2.w;
        acc[12] += v3.x; acc[13] += v3.y; acc[14] += v3.z; acc[15] += v3.w;
    }
    float dn = ds_l[t];
    float4 ov[4];
    #pragma unroll
    for (int q = 0; q < 4; ++q) {
        float4 sv = *(const float4*)&xs[t][q * 4];
        float4 o;
        o.x = dn * (acc[q * 4 + 0] + sv.x) + bias[c0 + q * 4 + 0];
        o.y = dn * (acc[q * 4 + 1] + sv.y) + bias[c0 + q * 4 + 1];
        o.z = dn * (acc[q * 4 + 2] + sv.z) + bias[c0 + q * 4 + 2];
        o.w = dn * (acc[q * 4 + 3] + sv.w) + bias[c0 + q * 4 + 3];
        o.x = o.x > 0.f ? o.x : 0.f;
        o.y = o.y > 0.f ? o.y : 0.f;
        o.z = o.z > 0.f ? o.z : 0.f;
        o.w = o.w > 0.f ? o.w : 0.f;
        ov[q] = o;
    }
    float* outp = &out_b[(size_t)(nbase + t) * HD + c0];
    #pragma unroll
    for (int q = 0; q < 4; ++q) *(float4*)&outp[q * 4] = ov[q];
}

// ---------------------------------------------------------------------------
// Fused sort_pool + conv1d + relu. grid (NB, 2 branches), block 512.
// ---------------------------------------------------------------------------
__global__ __launch_bounds__(512) void sortconv_k(const float* __restrict__ x,
                                                  const float* __restrict__ cwA,
                                                  const float* __restrict__ cwB,
                                                  const float* __restrict__ cbA,
                                                  const float* __restrict__ cbB,
                                                  float* __restrict__ cbuf) {
    __shared__ float v[512];
    __shared__ int   idx[512];
    __shared__ float xs[KP][CPAD];      // 15.8 KB
    __shared__ float wl[CO][5][HD];     // 80 KB  wl[o][kk][i]
    int g = blockIdx.x, br = blockIdx.y, t = threadIdx.x;
    const float* xb = x + (size_t)br * NN * HD;
    const float* convW = br ? cwB : cwA;
    const float* convb = br ? cbB : cbA;
    float* cb = cbuf + (size_t)br * NB * FEAT;

    v[t] = xb[(size_t)(g * NPG + t) * HD + (HD - 1)];
    idx[t] = t;
    for (int l = t; l < CO * 5 * HD; l += 512) {
        int o = l / (5 * HD), r = l % (5 * HD), kk = r / HD, i = r % HD;
        wl[o][kk][i] = convW[(o * HD + i) * 5 + kk];
    }
    __syncthreads();
    for (int k = 2; k <= 512; k <<= 1) {
        for (int j = k >> 1; j > 0; j >>= 1) {
            int ixj = t ^ j;
            if (ixj > t) {
                float va = v[t], vb = v[ixj];
                int ia = idx[t], ib = idx[ixj];
                bool aBefore = (va > vb) || (va == vb && ia < ib);
                bool dirDesc = ((t & k) == 0);
                if (dirDesc ? !aBefore : aBefore) {
                    v[t] = vb; v[ixj] = va;
                    idx[t] = ib; idx[ixj] = ia;
                }
            }
            __syncthreads();
        }
    }
    for (int l = t; l < KP * (HD / 4); l += 512) {      // 960 float4
        int r = l >> 5, c4 = l & 31;
        float4 vv = *(const float4*)&xb[(size_t)(g * NPG + idx[r]) * HD + c4 * 4];
        *(float4*)&xs[r][c4 * 4] = vv;
    }
    __syncthreads();
    for (int j = t; j < CO * CT; j += 512) {
        int o = j / CT, tt = j % CT;
        float acc = convb[o];
        #pragma unroll
        for (int kk = 0; kk < 5; ++kk) {
            const float* xr = &xs[tt + kk][0];
            const float* wr = &wl[o][kk][0];
            #pragma unroll 8
            for (int i4 = 0; i4 < HD / 4; ++i4) {
                float4 a = *(const float4*)&xr[i4 * 4];
                float4 w = *(const float4*)&wr[i4 * 4];
                acc += a.x * w.x + a.y * w.y + a.z * w.z + a.w * w.w;
            }
        }
        cb[g * FEAT + j] = acc > 0.f ? acc : 0.f;
    }
}

// ---------------------------------------------------------------------------
// Head
// ---------------------------------------------------------------------------
__global__ __launch_bounds__(128) void lin1_part(const float* __restrict__ cbuf,
                                                 const float* __restrict__ W,
                                                 float* __restrict__ out1p) {
    __shared__ float fs[128];
    int b = blockIdx.x, kc = blockIdx.y, t = threadIdx.x;
    int r0 = kc * 128;
    int r = r0 + t;
    fs[t] = (r < FEAT) ? cbuf[(size_t)b * FEAT + r]
                       : cbuf[(size_t)NB * FEAT + (size_t)b * FEAT + (r - FEAT)];
    __syncthreads();
    float acc = 0.f;
    #pragma unroll 8
    for (int rr = 0; rr < 128; ++rr)
        acc += fs[rr] * W[(size_t)(r0 + rr) * HD + t];
    out1p[((size_t)b * KCH + kc) * HD + t] = acc;
}

// lin1_red + lin2 + lin3 + final log_softmax + loss add. grid NB, block 128.
__global__ __launch_bounds__(128) void tail_k(const float* __restrict__ out1p,
                                              const float* __restrict__ b1,
                                              const float* __restrict__ W2,
                                              const float* __restrict__ b2,
                                              const float* __restrict__ W3,
                                              const float* __restrict__ b3,
                                              const float* __restrict__ loss,
                                              float* __restrict__ out) {
    __shared__ float o1[HD];
    __shared__ float o2[64];
    __shared__ float x3s[2];
    int b = blockIdx.x, t = threadIdx.x;
    float acc = b1[t];
    #pragma unroll
    for (int kc = 0; kc < KCH; ++kc) acc += out1p[((size_t)b * KCH + kc) * HD + t];
    o1[t] = acc > 0.f ? acc : 0.f;
    __syncthreads();
    if (t < 64) {
        float a2 = b2[t];
        #pragma unroll 8
        for (int r = 0; r < HD; ++r) a2 += o1[r] * W2[r * 64 + t];
        o2[t] = a2 > 0.f ? a2 : 0.f;
    }
    __syncthreads();
    if (t < 2) {
        float a3 = b3[t];
        for (int r = 0; r < 64; ++r) a3 += o2[r] * W3[r * 2 + t];
        x3s[t] = a3;
    }
    __syncthreads();
    if (t == 0) {
        float l0 = x3s[0], l1 = x3s[1];
        float m = fmaxf(l0, l1);
        float lse = m + logf(expf(l0 - m) + expf(l1 - m));
        float L = *loss;
        out[b * 2]     = l0 - lse + L;
        out[b * 2 + 1] = l1 - lse + L;
    }
}

// also zeroes the loss accumulator (runs before clip_k, stream-ordered)
__global__ __launch_bounds__(64) void norm_k(const float* __restrict__ cbuf,
                                             float* __restrict__ inv_norm,
                                             float* __restrict__ loss) {
    int i = blockIdx.x;            // 0..127 (64 sc rows then 64 fc rows)
    int t = threadIdx.x;
    if (i == 0 && t == 0) *loss = 0.f;
    const float* row = cbuf + (size_t)i * FEAT;
    float s = 0.f;
    for (int r = t; r < FEAT; r += 64) s += row[r] * row[r];
    #pragma unroll
    for (int o = 32; o; o >>= 1) s += __shfl_down(s, o);
    if (t == 0) inv_norm[i] = rsqrtf(s);
}

// grid (64, 2): blockIdx.x = i, blockIdx.y = branch. 512 threads.
__global__ __launch_bounds__(512) void clip_k(const float* __restrict__ cbuf,
                                              const float* __restrict__ inv_norm,
                                              float* __restrict__ loss) {
    __shared__ float ai_s[FEAT];
    __shared__ float dpS[8][64];
    __shared__ float dnS[8][64];
    int i = blockIdx.x, br = blockIdx.y;
    int t = threadIdx.x;
    const float* A  = cbuf + (br ? (size_t)NB * FEAT : 0);
    const float* Bm = cbuf + (br ? 0 : (size_t)NB * FEAT);
    const float* invA = inv_norm + (br ? 64 : 0);
    const float* invB = inv_norm + (br ? 0 : 64);
    for (int r = t; r < FEAT; r += 512) ai_s[r] = A[(size_t)i * FEAT + r];
    __syncthreads();
    int j = t & 63, rc = t >> 6;
    float dp = 0.f, dn = 0.f;
    #pragma unroll 8
    for (int r = rc * 104; r < rc * 104 + 104; ++r) {
        float a = ai_s[r];
        dp += a * Bm[(size_t)j * FEAT + r];
        dn += a * A[(size_t)j * FEAT + r];
    }
    dpS[rc][j] = dp; dnS[rc][j] = dn;
    __syncthreads();
    if (t < 64) {
        float dpt = 0.f, dnt = 0.f;
        #pragma unroll
        for (int c = 0; c < 8; ++c) { dpt += dpS[c][t]; dnt += dnS[c][t]; }
        float lp = dpt * invA[i] * invB[t] * 2.0f;                     // /TEMP
        float ln = (t == i) ? 0.0f : 0.8f * dnt * invA[i] * invA[t] * 2.0f;
        float m = fmaxf(lp, ln);
        #pragma unroll
        for (int o = 32; o; o >>= 1) m = fmaxf(m, __shfl_xor(m, o));
        float s = expf(lp - m) + expf(ln - m);
        #pragma unroll
        for (int o = 32; o; o >>= 1) s += __shfl_xor(s, o);
        float lse = m + logf(s);
        float lpi = __shfl(lp, i);
        if (t == 0) atomicAdd(loss, (lse - lpi) * (1.0f / 128.0f));
    }
}

// ---------------------------------------------------------------------------
extern "C" void kernel_launch(void* const* d_in, const int* in_sizes, int n_in,
                              void* d_out, int out_size, void* d_ws, size_t ws_size,
                              hipStream_t stream) {
    (void)in_sizes; (void)n_in; (void)out_size; (void)ws_size;

    char* w = (char*)d_ws;
    auto alloc = [&](size_t bytes) -> char* {
        char* p = w;
        w += (bytes + 255) & ~(size_t)255;
        return p;
    };

    unsigned short* csr_us  = (unsigned short*)alloc((size_t)2 * NE * 2);
    unsigned short* offs_us = (unsigned short*)alloc((size_t)2 * NB * OPG * 2);
    float* dis     = (float*)alloc((size_t)2 * NN * 4);
    float* xw      = (float*)alloc((size_t)2 * NN * HD * 4);
    float* buf0    = (float*)alloc((size_t)2 * NN * HD * 4);
    float* buf1    = (float*)alloc((size_t)2 * NN * HD * 4);
    float* cbuf    = (float*)alloc((size_t)2 * NB * FEAT * 4);
    float* inv_nrm = (float*)alloc(128 * 4);
    float* out1p   = (float*)alloc((size_t)NB * KCH * HD * 4);
    float* loss    = (float*)alloc(4);
    unsigned short* whiT = (unsigned short*)alloc((size_t)2 * 4 * HD * HD * 2);
    unsigned short* wloT = (unsigned short*)alloc((size_t)2 * 4 * HD * HD * 2);

    const float* sc_x  = (const float*)d_in[0];
    const float* fc_x  = (const float*)d_in[1];
    const int*   edgeA = (const int*)  d_in[2];
    const int*   edgeB = (const int*)  d_in[3];
    const float* WsA   = (const float*)d_in[4];
    const float* bsA   = (const float*)d_in[5];
    const float* WsB   = (const float*)d_in[6];
    const float* bsB   = (const float*)d_in[7];
    const float* cwA   = (const float*)d_in[8];
    const float* cbA   = (const float*)d_in[9];
    const float* cwB   = (const float*)d_in[10];
    const float* cbB   = (const float*)d_in[11];

    csr_build<<<128, 512, 0, stream>>>(edgeA, edgeB, csr_us, offs_us, dis);
    wprep_k<<<8, 1024, 0, stream>>>(WsA, WsB, whiT, wloT);

    // 4 GCN layers, both branches per dispatch
    const float* cur0 = sc_x;
    const float* cur1 = fc_x;
    float* bufs[2] = {buf0, buf1};
    for (int l = 0; l < 4; ++l) {
        gemm_mfma<<<dim3(NN / 128, 2), 256, 0, stream>>>(cur0, cur1, whiT, wloT, xw, l);
        float* nxt = bufs[l & 1];
        agg_graph<<<dim3(8, NB, 2), 512, 0, stream>>>(xw, csr_us, offs_us, dis,
                                                      bsA, bsB, nxt, l);
        cur0 = nxt;
        cur1 = nxt + (size_t)NN * HD;
    }

    // fused sort-pool + conv, both branches
    sortconv_k<<<dim3(NB, 2), 512, 0, stream>>>(cur0, cwA, cwB, cbA, cbB, cbuf);

    // head + CLIP loss (norm_k also zeroes the loss accumulator)
    norm_k<<<128, 64, 0, stream>>>(cbuf, inv_nrm, loss);
    clip_k<<<dim3(64, 2), 512, 0, stream>>>(cbuf, inv_nrm, loss);

    lin1_part<<<dim3(NB, KCH), 128, 0, stream>>>(cbuf, (const float*)d_in[12], out1p);
    tail_k<<<NB, 128, 0, stream>>>(out1p, (const float*)d_in[13],
                                   (const float*)d_in[14], (const float*)d_in[15],
                                   (const float*)d_in[16], (const float*)d_in[17],
                                   loss, (float*)d_out);
}